// Round 9
// baseline (600.576 us; speedup 1.0000x reference)
//
#include <hip/hip_runtime.h>
#include <math.h>

// Problem constants (fixed by setup_inputs)
#define B_ 1024
#define N_ 1024      // K dimension of the GEMM
#define T_ 16
#define H_ 4096
#define M_ (T_*B_)   // 16384 rows, row = t*B_ + b
#define NHB2_ 128    // h-slices of 32

#define LOG2C 0.69314718055994530942f

typedef int      i32x4  __attribute__((ext_vector_type(4)));
typedef _Float16 f16x8  __attribute__((ext_vector_type(8)));
typedef float    f32x16 __attribute__((ext_vector_type(16)));

// ---------------- numerics helpers ----------------

// atan2(y, x) for x > 0 (guaranteed: wre = 1 + e*cos >= 0).
// deg-11 odd minimax + reciprocal range reduction; |err| ~1e-5.
// HW-validated rounds 6-22 (absmax at comparison floor).
__device__ __forceinline__ float atan2_pos(float y, float x) {
    float ay = fabsf(y);
    float mn = fminf(ay, x), mx = fmaxf(ay, x);
    float r  = __fdividef(mn, mx);        // in [0,1]
    float t  = r * r;
    float p  = fmaf(t, -0.0117212f, 0.05265332f);
    p = fmaf(t, p, -0.11643287f);
    p = fmaf(t, p,  0.19354346f);
    p = fmaf(t, p, -0.33262347f);
    p = fmaf(t, p,  0.99997726f);
    float a = r * p;
    a = (ay > x) ? (1.5707963267948966f - a) : a;
    return (y < 0.0f) ? -a : a;
}

// fast-path log_cosh (fast atan)
__device__ __forceinline__ void log_cosh_f(float zr, float zi, float& lr, float& li) {
    float s = (zr < 0.0f) ? -1.0f : 1.0f;
    float a = zr * s;                    // >= 0
    float c = zi * s;
    float e = __expf(-2.0f * a);         // in (0,1]
    float s2, c2;
    __sincosf(2.0f * c, &s2, &c2);
    float wre = fmaf(e, c2, 1.0f);       // >= 0 always
    float wim = -e * s2;
    float mag2 = fmaf(wre, wre, wim * wim);
    lr = a + 0.5f * __logf(mag2) - LOG2C;
    li = c + atan2_pos(wim, wre);
}

// fallback-path log_cosh (libm atan2)
__device__ __forceinline__ void log_cosh_c(float zr, float zi, float& lr, float& li) {
    float s = (zr < 0.0f) ? -1.0f : 1.0f;
    float a = zr * s;
    float c = zi * s;
    float e = __expf(-2.0f * a);
    float s2, c2;
    __sincosf(2.0f * c, &s2, &c2);
    float wre = fmaf(e, c2, 1.0f);
    float wim = -e * s2;
    float mag2 = fmaf(wre, wre, wim * wim);
    lr = a + 0.5f * __logf(mag2) - LOG2C;
    li = c + atan2f(wim, wre);
}

__device__ __forceinline__ void gll16(const void* g, void* l) {
    __builtin_amdgcn_global_load_lds(
        (const __attribute__((address_space(1))) unsigned int*)g,
        (__attribute__((address_space(3))) unsigned int*)l,
        16, 0, 0);
}

// =======================================================================
// FAST PATH (f16 MFMA, W-through-LDS hybrid GEMM, 64-row waves, JIT A,
// 2 blocks/CU).
// r23 post-mortem of r22: JIT-A halved the slots but the 64-row tile STILL
// spilled at launch_bounds(256,3): VGPR 84, WRITE 295 MB / FETCH +251 MB
// (matched scratch round-trip), 435 us. The tile's live state (64 acc +
// 16 W frag + A transients + dual epilogue temps) does not fit ~168 VGPR.
// This round: ONE variable -- __launch_bounds__(256,2) (cap ~256 VGPR).
// The ~150-reg live set now fits with slack; the compiler can also hoist
// A loads band-deep (its strength, cf r20 VGPR=48). Cost: 2 blocks/CU
// (8 waves/CU). Acceptable: per-wave ILP is high (two independent MFMA
// chains x 4 k-steps between barriers; W prefetch aged a full band).
// Guard: WRITE_SIZE back to ~33 MB / FETCH ~140 MB = spill gone.
// Geometry unchanged from r22: 4 ds_read_b128 feed 8 MFMAs (1:2), halving
// the LDS pipe that r20 identified as the top pipe (39%).
// Bitwise-identical accumulation order => absmax stays 0.125.
// ws layout (bytes):
//   A16  [K/8][M] 16B chunks (8 f16 of consecutive k)   33.55 MB
//   Wr16,Wi16 [K/8][H] 16B chunks (f16, W^T)            2 x 8.39 MB
//   part float4[128][M]  33.55 MB ;  red float4[M]  0.26 MB
// =======================================================================

// --- prep A: gather + f16 convert. One thread = one 16B chunk (8 elems).
__global__ __launch_bounds__(256) void prep_A16(
    const float* __restrict__ x, const int* __restrict__ trans,
    signed char* __restrict__ A16)
{
    int ci = blockIdx.x * 256 + threadIdx.x;   // kc*M_ + row, kc in 0..127
    int row = ci & (M_ - 1);
    int kc  = ci >> 14;
    int t   = row >> 10, b = row & (B_ - 1);
    const int* __restrict__ trow = trans + t * N_ + kc * 8;
    const float* __restrict__ xr = x + (size_t)b * N_;
    alignas(16) _Float16 buf[8];
    #pragma unroll
    for (int j = 0; j < 8; j++) buf[j] = (_Float16)xr[trow[j]];
    *(uint4*)(A16 + (size_t)ci * 16) = *(uint4*)buf;
}

// --- prep W: transpose-pack + f16 convert. blockIdx.y: 0->Wr, 1->Wi.
__global__ __launch_bounds__(256) void prep_W16(
    const float* __restrict__ Wr, const float* __restrict__ Wi,
    signed char* __restrict__ Wr16, signed char* __restrict__ Wi16)
{
    int ci = blockIdx.x * 256 + threadIdx.x;   // kc*H_ + h, kc in 0..127
    int h  = ci & (H_ - 1);
    int kc = ci >> 12;
    const float* __restrict__ W = blockIdx.y ? Wi : Wr;
    signed char* __restrict__ D = blockIdx.y ? Wi16 : Wr16;
    alignas(16) _Float16 buf[8];
    #pragma unroll
    for (int j = 0; j < 8; j++)
        buf[j] = (_Float16)W[(size_t)(kc * 8 + j) * H_ + h];
    *(uint4*)(D + (size_t)ci * 16) = *(uint4*)buf;
}

// --- main f16 MFMA GEMM: W double-buffered through LDS; each wave owns
//     TWO 32-row sub-tiles (W-fragment reuse); A loaded JIT from global.
// Structure: block = 4 waves x 64 rows = 256 rows x one 32-h slice; W
// staged into 2 x 16 KB LDS buffers per K=128 band (8 bands, 8 barriers;
// prefetch for band s+1 issued at TOP of band s so the barrier's vmcnt(0)
// drain is ~aged-out).
// MFMA operands SWAPPED (A-op = W, B-op = xt): D[h(regs)][m(cols)] -- the
// h-reduction is in-lane adds + ONE shuffle; partial write is coalesced.
// Layouts (dtype-independent, HW-verified r8-22): A/B frag lane l holds
// 16B chunk k8=(l>>5), index (l&31); C/D col=lane&31,
// row=(reg&3)+8*(reg>>2)+4*(lane>>5) [m74/m101].
// Per ks (K=32): 4 ds_read_b128 + 4 global 16B (A JIT) + 8 MFMA.
__global__ __launch_bounds__(256, 2) void gemm_f16(
    const signed char* __restrict__ A16,
    const signed char* __restrict__ Wr16, const signed char* __restrict__ Wi16,
    const float* __restrict__ br, const float* __restrict__ bi,
    float4* __restrict__ part)
{
    // [buf(2)][arr(2)][q(16)][h(32)] 16B chunks
    __shared__ __align__(16) signed char sW[32768];

    const int tid  = threadIdx.x;
    const int l    = tid & 63;
    const int w    = tid >> 6;
    const int c32  = l & 31;
    const int half = l >> 5;
    const int bx   = blockIdx.x;
    const int hs   = bx & 127;       // 0..127  h-slice (fastest-varying)
    const int mb   = bx >> 7;        // 0..63   m-block of 256 rows
    const int m0   = mb * 256 + w * 64;   // wave's 64-row tile (2 x 32)
    const int rowA = m0 + c32;

    // A stream: lane l reads chunks 2i+half (i=0..63), rows rowA / rowA+32.
    const signed char* pA = A16 + ((size_t)half * M_ + rowA) * 16;
    const size_t strA = (size_t)2 * M_ * 16;   // advance 2 k8-chunks

    const int q_lo = tid >> 5;      // 0..7 (staging k-chunk low bits)
    const int h_st = tid & 31;      // staging h index
    const size_t woff = ((size_t)q_lo * H_ + hs * 32 + h_st) * 16;
    const signed char* wsrc0 = Wr16 + woff;
    const signed char* wsrc1 = Wi16 + woff;
    const int ldst = tid * 16;      // LDS dest: uniform + lane*16
    const size_t WQ8 = (size_t)8 * H_ * 16;    // 8 k8-chunks of W

    f32x16 aR0 = {}, aI0 = {}, aR1 = {}, aI1 = {};

    // ---- prologue: band 0 W into buf 0
    gll16(wsrc0,       sW + 0 * 4096 + ldst);   // arr0 q0..7
    gll16(wsrc0 + WQ8, sW + 1 * 4096 + ldst);   // arr0 q8..15
    gll16(wsrc1,       sW + 2 * 4096 + ldst);   // arr1 q0..7
    gll16(wsrc1 + WQ8, sW + 3 * 4096 + ldst);   // arr1 q8..15
    __syncthreads();

    const int lbase = half * 512 + c32 * 16;    // per-lane LDS read base
    const size_t WBAND = (size_t)16 * H_ * 16;  // per-band W bytes per array

    #pragma unroll
    for (int s = 0; s < 8; s++) {
        const int cur = s & 1;
        const int nxt = cur ^ 1;

        // ---- prefetch band s+1 W FIRST: 4 gll16 -> other LDS buffer.
        //      By the band-end barrier these are ~4 ks old => vmcnt(0)
        //      drain ~free.
        if (s < 7) {
            size_t wadd = (size_t)(s + 1) * WBAND;
            gll16(wsrc0 + wadd,       sW + nxt * 16384 + 0 * 4096 + ldst);
            gll16(wsrc0 + wadd + WQ8, sW + nxt * 16384 + 1 * 4096 + ldst);
            gll16(wsrc1 + wadd,       sW + nxt * 16384 + 2 * 4096 + ldst);
            gll16(wsrc1 + wadd + WQ8, sW + nxt * 16384 + 3 * 4096 + ldst);
        }

        // ---- 4 k-steps (K=32 each) from buf[cur]; A loaded JIT.
        //      4 ds_read + 4 global 16B feed 8 MFMA.
        #pragma unroll
        for (int ks = 0; ks < 4; ks++) {
            int off = cur * 16384 + ks * 2048 + lbase;   // q = ks*4 + 2j + half
            f16x8 wr0 = *(const f16x8*)&sW[off];                  // arr0 j0
            f16x8 wr1 = *(const f16x8*)&sW[off + 1024];           // arr0 j1
            f16x8 wi0 = *(const f16x8*)&sW[off + 8192];           // arr1 j0
            f16x8 wi1 = *(const f16x8*)&sW[off + 8192 + 1024];    // arr1 j1
            // j = 0
            f16x8 a00 = *(const f16x8*)pA;
            f16x8 a10 = *(const f16x8*)(pA + 512);
            pA += strA;
            // j = 1
            f16x8 a01 = *(const f16x8*)pA;
            f16x8 a11 = *(const f16x8*)(pA + 512);
            pA += strA;
            // swapped operands: D[h][m] += W^T[h][k] * xt[m][k]
            aR0 = __builtin_amdgcn_mfma_f32_32x32x16_f16(wr0, a00, aR0, 0, 0, 0);
            aI0 = __builtin_amdgcn_mfma_f32_32x32x16_f16(wi0, a00, aI0, 0, 0, 0);
            aR1 = __builtin_amdgcn_mfma_f32_32x32x16_f16(wr0, a10, aR1, 0, 0, 0);
            aI1 = __builtin_amdgcn_mfma_f32_32x32x16_f16(wi0, a10, aI1, 0, 0, 0);
            aR0 = __builtin_amdgcn_mfma_f32_32x32x16_f16(wr1, a01, aR0, 0, 0, 0);
            aI0 = __builtin_amdgcn_mfma_f32_32x32x16_f16(wi1, a01, aI0, 0, 0, 0);
            aR1 = __builtin_amdgcn_mfma_f32_32x32x16_f16(wr1, a11, aR1, 0, 0, 0);
            aI1 = __builtin_amdgcn_mfma_f32_32x32x16_f16(wi1, a11, aI1, 0, 0, 0);
        }
        if (s < 7) __syncthreads();
    }

    // ---- epilogue: lane = one output row per sub-tile; regs = 16 h values.
    // acc IS t directly (f32 accumulate). br/bi loaded once, used by both
    // sub-tiles. Per sub-tile: in-lane sum then ONE shuffle.
    const int hbase = hs * 32 + 4 * half;
    float pr0 = 0.f, pi0 = 0.f, nr0 = 0.f, ni0 = 0.f;
    float pr1 = 0.f, pi1 = 0.f, nr1 = 0.f, ni1 = 0.f;
    #pragma unroll
    for (int reg = 0; reg < 16; reg++) {
        int h = hbase + (reg & 3) + 8 * (reg >> 2);
        float brv = br[h], biv = bi[h];
        float lr1, li1, lr2, li2;
        // sub-tile 0
        log_cosh_f(aR0[reg] + brv, aI0[reg] + biv, lr1, li1);
        log_cosh_f(brv - aR0[reg], biv - aI0[reg], lr2, li2);
        pr0 += lr1; pi0 += li1; nr0 += lr2; ni0 += li2;
        // sub-tile 1
        log_cosh_f(aR1[reg] + brv, aI1[reg] + biv, lr1, li1);
        log_cosh_f(brv - aR1[reg], biv - aI1[reg], lr2, li2);
        pr1 += lr1; pi1 += li1; nr1 += lr2; ni1 += li2;
    }
    pr0 += __shfl_xor(pr0, 32, 64);
    pi0 += __shfl_xor(pi0, 32, 64);
    nr0 += __shfl_xor(nr0, 32, 64);
    ni0 += __shfl_xor(ni0, 32, 64);
    pr1 += __shfl_xor(pr1, 32, 64);
    pi1 += __shfl_xor(pi1, 32, 64);
    nr1 += __shfl_xor(nr1, 32, 64);
    ni1 += __shfl_xor(ni1, 32, 64);
    if (half == 0) {
        // coalesced: 32 lanes write 512B; each (hs,row) written exactly once
        part[(size_t)hs * M_ + m0 + c32]      = make_float4(pr0, pi0, nr0, ni0);
        part[(size_t)hs * M_ + m0 + 32 + c32] = make_float4(pr1, pi1, nr1, ni1);
    }
}

// --- reduce the 128 h-slice partials per row ---
__global__ __launch_bounds__(64) void reduce_hb(
    const float4* __restrict__ part, float4* __restrict__ red)
{
    int row = blockIdx.x * 64 + threadIdx.x;
    float a0 = 0.f, a1 = 0.f, a2 = 0.f, a3 = 0.f;
    #pragma unroll 8
    for (int hb = 0; hb < NHB2_; hb++) {
        float4 v = part[(size_t)hb * M_ + row];
        a0 += v.x; a1 += v.y; a2 += v.z; a3 += v.w;
    }
    red[row] = make_float4(a0, a1, a2, a3);
}

// --- final logsumexp over 32 complex values per batch element ---
__global__ __launch_bounds__(64) void lse_final(
    const float4* __restrict__ red, float* __restrict__ out, int mode)
{
    int b = blockIdx.x * 64 + threadIdx.x;
    float re[32], im[32];
    #pragma unroll
    for (int t = 0; t < T_; t++) {
        float4 v = red[t * B_ + b];
        re[t]      = v.x; im[t]      = v.y;
        re[16 + t] = v.z; im[16 + t] = v.w;
    }
    float m = re[0];
    #pragma unroll
    for (int k = 1; k < 32; k++) m = fmaxf(m, re[k]);
    float Sr = 0.f, Si = 0.f;
    #pragma unroll
    for (int k = 0; k < 32; k++) {
        float mag = expf(re[k] - m);
        float s, c;
        sincosf(im[k], &s, &c);   // |im| can be tens of rad: libm reduction
        Sr = fmaf(mag, c, Sr);
        Si = fmaf(mag, s, Si);
    }
    float ore = 0.5f * logf(fmaf(Sr, Sr, Si * Si)) + m;
    float oim = atan2f(Si, Sr);
    if (mode == 0) out[b] = ore;
    else { out[b] = ore; out[B_ + b] = oim; }
}

// =======================================================================
// FALLBACK PATH — round-4 fp32 kernels (verified passing), used only if
// ws_size is too small for the packs.
// =======================================================================
#define FBM 128
#define FBH 64
#define FHC 4
#define FHBG (H_/(FBH*FHC))
#define FBK 16
#define FASTR 132
#define FPS (FHBG*M_)

__global__ __launch_bounds__(256, 3) void gemm_epi_fb(
    const float* __restrict__ x, const int* __restrict__ trans,
    const float* __restrict__ Wr, const float* __restrict__ Wi,
    const float* __restrict__ br, const float* __restrict__ bi,
    float* __restrict__ part)
{
    __shared__ float As[FBK * FASTR];
    __shared__ float Brs[FBK * FBH];
    __shared__ float Bis[FBK * FBH];

    const int tid = threadIdx.x;
    const int tx = tid & 15;
    const int ty = tid >> 4;
    const int hbg = blockIdx.x;
    const int m0 = blockIdx.y * FBM;
    const int t_band = m0 >> 10;
    const int* __restrict__ trow = trans + t_band * N_;

    float pr[8] = {}, pi[8] = {}, nr[8] = {}, ni[8] = {};

    for (int hc = 0; hc < FHC; hc++) {
        const int h0 = (hbg * FHC + hc) * FBH;
        float accre[8][4] = {}, accim[8][4] = {};
        for (int k0 = 0; k0 < N_; k0 += FBK) {
            #pragma unroll
            for (int p = 0; p < 8; p++) {
                int idx = tid + p * 256;
                int kk = idx & 15, r = idx >> 4;
                int b = (m0 + r) & (B_ - 1);
                As[kk * FASTR + r] = x[(size_t)b * N_ + trow[k0 + kk]];
            }
            {
                int r = tid >> 4, c4 = tid & 15;
                *(float4*)(Brs + r * FBH + c4 * 4) =
                    *(const float4*)(Wr + (size_t)(k0 + r) * H_ + h0 + c4 * 4);
                *(float4*)(Bis + r * FBH + c4 * 4) =
                    *(const float4*)(Wi + (size_t)(k0 + r) * H_ + h0 + c4 * 4);
            }
            __syncthreads();
            #pragma unroll
            for (int k = 0; k < FBK; k++) {
                float a[8], wr[4], wi[4];
                *(float4*)&a[0]  = *(float4*)&As[k * FASTR + ty * 8];
                *(float4*)&a[4]  = *(float4*)&As[k * FASTR + ty * 8 + 4];
                *(float4*)&wr[0] = *(float4*)&Brs[k * FBH + tx * 4];
                *(float4*)&wi[0] = *(float4*)&Bis[k * FBH + tx * 4];
                #pragma unroll
                for (int i = 0; i < 8; i++)
                    #pragma unroll
                    for (int j = 0; j < 4; j++) {
                        accre[i][j] = fmaf(a[i], wr[j], accre[i][j]);
                        accim[i][j] = fmaf(a[i], wi[j], accim[i][j]);
                    }
            }
            __syncthreads();
        }
        float brv[4], biv[4];
        #pragma unroll
        for (int j = 0; j < 4; j++) {
            brv[j] = br[h0 + tx * 4 + j];
            biv[j] = bi[h0 + tx * 4 + j];
        }
        #pragma unroll
        for (int i = 0; i < 8; i++)
            #pragma unroll
            for (int j = 0; j < 4; j++) {
                float tr = accre[i][j], ti = accim[i][j];
                float lr, li;
                log_cosh_c(tr + brv[j], ti + biv[j], lr, li);
                pr[i] += lr; pi[i] += li;
                log_cosh_c(brv[j] - tr, biv[j] - ti, lr, li);
                nr[i] += lr; ni[i] += li;
            }
    }
    #pragma unroll
    for (int i = 0; i < 8; i++) {
        float a0 = pr[i], a1 = pi[i], a2 = nr[i], a3 = ni[i];
        #pragma unroll
        for (int off = 1; off < 16; off <<= 1) {
            a0 += __shfl_xor(a0, off, 64);
            a1 += __shfl_xor(a1, off, 64);
            a2 += __shfl_xor(a2, off, 64);
            a3 += __shfl_xor(a3, off, 64);
        }
        if (tx == 0) {
            int row = m0 + ty * 8 + i;
            part[0 * FPS + hbg * M_ + row] = a0;
            part[1 * FPS + hbg * M_ + row] = a1;
            part[2 * FPS + hbg * M_ + row] = a2;
            part[3 * FPS + hbg * M_ + row] = a3;
        }
    }
}

__global__ __launch_bounds__(256) void sum_lse_fb(
    const float* __restrict__ part, float* __restrict__ out, int mode)
{
    int b = blockIdx.x * 256 + threadIdx.x;
    float re[32], im[32];
    #pragma unroll
    for (int t = 0; t < T_; t++) {
        int row = t * B_ + b;
        float a0 = 0.f, a1 = 0.f, a2 = 0.f, a3 = 0.f;
        for (int hb = 0; hb < FHBG; hb++) {
            a0 += part[0 * FPS + hb * M_ + row];
            a1 += part[1 * FPS + hb * M_ + row];
            a2 += part[2 * FPS + hb * M_ + row];
            a3 += part[3 * FPS + hb * M_ + row];
        }
        re[t]      = a0; im[t]      = a1;
        re[16 + t] = a2; im[16 + t] = a3;
    }
    float m = re[0];
    #pragma unroll
    for (int k = 1; k < 32; k++) m = fmaxf(m, re[k]);
    float Sr = 0.f, Si = 0.f;
    #pragma unroll
    for (int k = 0; k < 32; k++) {
        float mag = expf(re[k] - m);
        float s, c;
        sincosf(im[k], &s, &c);
        Sr = fmaf(mag, c, Sr);
        Si = fmaf(mag, s, Si);
    }
    float ore = 0.5f * logf(fmaf(Sr, Sr, Si * Si)) + m;
    float oim = atan2f(Si, Sr);
    if (mode == 0) out[b] = ore;
    else { out[b] = ore; out[B_ + b] = oim; }
}

// =======================================================================

extern "C" void kernel_launch(void* const* d_in, const int* in_sizes, int n_in,
                              void* d_out, int out_size, void* d_ws, size_t ws_size,
                              hipStream_t stream) {
    const float *x = nullptr, *Wr = nullptr, *Wi = nullptr, *br = nullptr, *bi = nullptr;
    const int *trans = nullptr;
    for (int i = 0; i < n_in; i++) {
        int s = in_sizes[i];
        if (s == B_ * N_ && !x)            x  = (const float*)d_in[i];
        else if (s == N_ * H_)             { if (!Wr) Wr = (const float*)d_in[i];
                                             else if (!Wi) Wi = (const float*)d_in[i]; }
        else if (s == H_)                  { if (!br) br = (const float*)d_in[i];
                                             else if (!bi) bi = (const float*)d_in[i]; }
        else if (s == T_ * N_ && !trans)   trans = (const int*)d_in[i];
    }
    if (!x)     x     = (const float*)d_in[0];
    if (!Wr)    Wr    = (const float*)d_in[1];
    if (!Wi)    Wi    = (const float*)d_in[2];
    if (!br)    br    = (const float*)d_in[3];
    if (!bi)    bi    = (const float*)d_in[4];
    if (!trans) trans = (const int*)d_in[5];

    float* out = (float*)d_out;
    const int mode = (out_size == B_) ? 0 : 1;

    const size_t NEED = (size_t)2 * M_ * N_          // A16 (f16)
                      + (size_t)4 * N_ * H_          // Wr16+Wi16 (f16)
                      + (size_t)NHB2_ * M_ * 16      // float4 partials
                      + (size_t)M_ * 16;             // float4 reduced

    if (ws_size >= NEED) {
        signed char* A16  = (signed char*)d_ws;
        signed char* Wr16 = A16  + (size_t)2 * M_ * N_;
        signed char* Wi16 = Wr16 + (size_t)2 * N_ * H_;
        float4* part = (float4*)(Wi16 + (size_t)2 * N_ * H_);
        float4* red  = part + (size_t)NHB2_ * M_;

        prep_A16<<<(M_ * (N_ / 8)) / 256, 256, 0, stream>>>(x, trans, A16);
        dim3 gw((N_ / 8) * H_ / 256, 2);
        prep_W16<<<gw, 256, 0, stream>>>(Wr, Wi, Wr16, Wi16);
        gemm_f16<<<64 * 128, 256, 0, stream>>>(A16, Wr16, Wi16,
                                               br, bi, part);
        reduce_hb<<<M_ / 64, 64, 0, stream>>>(part, red);
        lse_final<<<B_ / 64, 64, 0, stream>>>(red, out, mode);
    } else {
        float* part = (float*)d_ws;
        dim3 grid(FHBG, M_ / FBM);
        gemm_epi_fb<<<grid, 256, 0, stream>>>(x, trans, Wr, Wi, br, bi, part);
        sum_lse_fb<<<B_ / 256, 256, 0, stream>>>(part, out, mode);
    }
}

// Round 11
// 536.191 us; speedup vs baseline: 1.1201x; 1.1201x over previous
//
#include <hip/hip_runtime.h>
#include <math.h>

// Problem constants (fixed by setup_inputs)
#define B_ 1024
#define N_ 1024      // K dimension of the GEMM
#define T_ 16
#define H_ 4096
#define M_ (T_*B_)   // 16384 rows, row = t*B_ + b
#define NHB2_ 128    // h-slices of 32

#define LOG2C 0.69314718055994530942f

typedef int      i32x4  __attribute__((ext_vector_type(4)));
typedef _Float16 f16x8  __attribute__((ext_vector_type(8)));
typedef float    f32x16 __attribute__((ext_vector_type(16)));

// ---------------- numerics helpers ----------------

// full-range fast atan2 (deg-11 odd minimax, reciprocal range reduction).
// |err| ~1e-5. Used ONCE per 16-term phasor product (not per term), so the
// approximation error contribution is 16x smaller than the old per-term use.
__device__ __forceinline__ float atan2_full(float y, float x) {
    float ax = fabsf(x), ay = fabsf(y);
    float mn = fminf(ay, ax), mx = fmaxf(ay, ax);
    float r  = __fdividef(mn, mx);        // in [0,1]
    float t  = r * r;
    float p  = fmaf(t, -0.0117212f, 0.05265332f);
    p = fmaf(t, p, -0.11643287f);
    p = fmaf(t, p,  0.19354346f);
    p = fmaf(t, p, -0.33262347f);
    p = fmaf(t, p,  0.99997726f);
    float a = r * p;
    a = (ay > ax) ? (1.5707963267948966f - a) : a;
    a = (x < 0.0f) ? (3.14159265358979323846f - a) : a;
    return (y < 0.0f) ? -a : a;
}

// fallback-path log_cosh (libm atan2)
__device__ __forceinline__ void log_cosh_c(float zr, float zi, float& lr, float& li) {
    float s = (zr < 0.0f) ? -1.0f : 1.0f;
    float a = zr * s;
    float c = zi * s;
    float e = __expf(-2.0f * a);
    float s2, c2;
    __sincosf(2.0f * c, &s2, &c2);
    float wre = fmaf(e, c2, 1.0f);
    float wim = -e * s2;
    float mag2 = fmaf(wre, wre, wim * wim);
    lr = a + 0.5f * __logf(mag2) - LOG2C;
    li = c + atan2f(wim, wre);
}

__device__ __forceinline__ void gll16(const void* g, void* l) {
    __builtin_amdgcn_global_load_lds(
        (const __attribute__((address_space(1))) unsigned int*)g,
        (__attribute__((address_space(3))) unsigned int*)l,
        16, 0, 0);
}

// =======================================================================
// FAST PATH (f16 MFMA, W-through-LDS hybrid GEMM, PHASOR-PRODUCT epilogue).
// r24 post-mortem chain: r21/r22/r23 (64-row tile) all dead -- spills at
// 3 blk/CU (WRITE 295-537 MB), latency-bound at 2 blk/CU (491 us @ 23%
// occ). REVERTED to r20 (419 us, VGPR 48, WRITE 33 MB).
// r20's real bottleneck (mis-read for 3 rounds): VALUBusy 77.9 is the TOP
// pipe (MFMA/VALU are separate pipes, m114): the epilogue's 2x log_cosh
// per (row,h) = 134M evals x ~90 cyc/wave ~= 300+ us of pure VALU -- the
// kernel's floor. LDS was 39%, MFMA 33%.
// This round: PHASOR-PRODUCT epilogue. Per-term angles are only ever
// SUMMED and finally consumed mod 2pi (lse sincos), so accumulate the
// complex product P = prod(w_h) (4 VALU/term; |w| in (0,2], 16 terms =>
// |P| in [6e-6, 65536], f32-safe) and take ONE log + ONE atan2 per 16
// terms: sum lr = sum a - 16*LOG2 + 0.5*log|P|^2 (exact: log of product
// = sum of logs); sum li = sum c + angle(P)  (mod 2pi -- invisible to
// reduce_hb sums and lse sincos; mode-1 oim is principal-value atan2 of
// the final sums, also unaffected). Per-pair epilogue cost 180 -> ~112
// cyc (-38%); predicted VALUBusy 78 -> ~60, gemm 419 -> ~330.
// GEMM loop: byte-identical to r20 (VGPR 48, no spill). Guards: WRITE
// ~33 MB, VGPR <= ~64.
// ws layout (bytes):
//   A16  [K/8][M] 16B chunks (8 f16 of consecutive k)   33.55 MB
//   Wr16,Wi16 [K/8][H] 16B chunks (f16, W^T)            2 x 8.39 MB
//   part float4[128][M]  33.55 MB ;  red float4[M]  0.26 MB
// =======================================================================

// --- prep A: gather + f16 convert. One thread = one 16B chunk (8 elems).
__global__ __launch_bounds__(256) void prep_A16(
    const float* __restrict__ x, const int* __restrict__ trans,
    signed char* __restrict__ A16)
{
    int ci = blockIdx.x * 256 + threadIdx.x;   // kc*M_ + row, kc in 0..127
    int row = ci & (M_ - 1);
    int kc  = ci >> 14;
    int t   = row >> 10, b = row & (B_ - 1);
    const int* __restrict__ trow = trans + t * N_ + kc * 8;
    const float* __restrict__ xr = x + (size_t)b * N_;
    alignas(16) _Float16 buf[8];
    #pragma unroll
    for (int j = 0; j < 8; j++) buf[j] = (_Float16)xr[trow[j]];
    *(uint4*)(A16 + (size_t)ci * 16) = *(uint4*)buf;
}

// --- prep W: transpose-pack + f16 convert. blockIdx.y: 0->Wr, 1->Wi.
__global__ __launch_bounds__(256) void prep_W16(
    const float* __restrict__ Wr, const float* __restrict__ Wi,
    signed char* __restrict__ Wr16, signed char* __restrict__ Wi16)
{
    int ci = blockIdx.x * 256 + threadIdx.x;   // kc*H_ + h, kc in 0..127
    int h  = ci & (H_ - 1);
    int kc = ci >> 12;
    const float* __restrict__ W = blockIdx.y ? Wi : Wr;
    signed char* __restrict__ D = blockIdx.y ? Wi16 : Wr16;
    alignas(16) _Float16 buf[8];
    #pragma unroll
    for (int j = 0; j < 8; j++)
        buf[j] = (_Float16)W[(size_t)(kc * 8 + j) * H_ + h];
    *(uint4*)(D + (size_t)ci * 16) = *(uint4*)buf;
}

// --- main f16 MFMA GEMM: W double-buffered through LDS, A batch-prefetched.
// Structure (== r20, 419 us verified): block = 4 waves x 32 rows = 128 rows
// x one 32-h slice; W staged into 2 x 16 KB LDS buffers per K=128 band
// (8 bands, 8 barriers; prefetch for band s+1 issued at TOP of band s so
// the barrier's vmcnt(0) drain is ~aged-out); A streams global->VGPR in
// per-band batches of 8 chunk loads (compiler collapses the slots: VGPR 48).
// MFMA operands SWAPPED (A-op = W, B-op = xt): D[h(regs)][m(cols)] -- the
// h-reduction is in-lane adds + ONE shuffle; partial write is coalesced.
// Layouts (dtype-independent, HW-verified r8-23): A/B frag lane l holds
// 16B chunk k8=(l>>5), index (l&31); C/D col=lane&31,
// row=(reg&3)+8*(reg>>2)+4*(lane>>5) [m74/m101].
__global__ __launch_bounds__(256, 3) void gemm_f16(
    const signed char* __restrict__ A16,
    const signed char* __restrict__ Wr16, const signed char* __restrict__ Wi16,
    const float* __restrict__ br, const float* __restrict__ bi,
    float4* __restrict__ part)
{
    // [buf(2)][arr(2)][q(16)][h(32)] 16B chunks
    __shared__ __align__(16) signed char sW[32768];

    const int tid  = threadIdx.x;
    const int l    = tid & 63;
    const int w    = tid >> 6;
    const int c32  = l & 31;
    const int half = l >> 5;
    const int bx   = blockIdx.x;
    const int hs   = bx & 127;       // 0..127  h-slice (fastest-varying)
    const int mb   = bx >> 7;        // 0..127  m-block (mb-major: A L2-hot,
                                     //  W co-streamed from L3 by the group)
    const int m0   = mb * 128 + w * 32;   // wave's 32-row tile
    const int rowA = m0 + c32;

    // A chunk pointer: slot p holds chunk band*16 + 2p + half, row rowA
    const signed char* pA = A16 + ((size_t)half * M_ + rowA) * 16;
    const size_t strA = (size_t)2 * M_ * 16;   // advance 2 k8-chunks

    const int q_lo = tid >> 5;      // 0..7 (staging k-chunk low bits)
    const int h_st = tid & 31;      // staging h index
    const size_t woff = ((size_t)q_lo * H_ + hs * 32 + h_st) * 16;
    const signed char* wsrc0 = Wr16 + woff;
    const signed char* wsrc1 = Wi16 + woff;
    const int ldst = tid * 16;      // LDS dest: uniform + lane*16
    const size_t WQ8 = (size_t)8 * H_ * 16;    // 8 k8-chunks of W

    f32x16 accR = {}, accI = {};

    // A slots: [band-parity][8], batch-loaded one band ahead
    f16x8 aS[2][8];

    // ---- prologue: band 0 A batch + band 0 W into buf 0
    #pragma unroll
    for (int p = 0; p < 8; p++) {
        aS[0][p] = *(const f16x8*)pA;  pA += strA;
    }
    gll16(wsrc0,       sW + 0 * 4096 + ldst);   // arr0 q0..7
    gll16(wsrc0 + WQ8, sW + 1 * 4096 + ldst);   // arr0 q8..15
    gll16(wsrc1,       sW + 2 * 4096 + ldst);   // arr1 q0..7
    gll16(wsrc1 + WQ8, sW + 3 * 4096 + ldst);   // arr1 q8..15
    __syncthreads();

    const int lbase = half * 512 + c32 * 16;    // per-lane LDS read base
    const size_t WBAND = (size_t)16 * H_ * 16;  // per-band W bytes per array

    #pragma unroll
    for (int s = 0; s < 8; s++) {
        const int cur = s & 1;
        const int nxt = cur ^ 1;

        // ---- prefetch band s+1 FIRST: 4 gll16 -> other LDS buffer, plus
        //      its 8 A chunk loads -> other slot set. By the band-end
        //      barrier these are ~4 ks old => vmcnt(0) drain ~free.
        if (s < 7) {
            size_t wadd = (size_t)(s + 1) * WBAND;
            gll16(wsrc0 + wadd,       sW + nxt * 16384 + 0 * 4096 + ldst);
            gll16(wsrc0 + wadd + WQ8, sW + nxt * 16384 + 1 * 4096 + ldst);
            gll16(wsrc1 + wadd,       sW + nxt * 16384 + 2 * 4096 + ldst);
            gll16(wsrc1 + wadd + WQ8, sW + nxt * 16384 + 3 * 4096 + ldst);
            #pragma unroll
            for (int p = 0; p < 8; p++) {
                aS[nxt][p] = *(const f16x8*)pA;  pA += strA;
            }
        }

        // ---- 4 k-steps (K=32 each) from buf[cur]
        #pragma unroll
        for (int ks = 0; ks < 4; ks++) {
            int off = cur * 16384 + ks * 2048 + lbase;   // q = ks*4 + 2j + half
            f16x8 wr0 = *(const f16x8*)&sW[off];                  // arr0 j0
            f16x8 wr1 = *(const f16x8*)&sW[off + 1024];           // arr0 j1
            f16x8 wi0 = *(const f16x8*)&sW[off + 8192];           // arr1 j0
            f16x8 wi1 = *(const f16x8*)&sW[off + 8192 + 1024];    // arr1 j1
            // swapped operands: D[h][m] += W^T[h][k] * xt[m][k]
            accR = __builtin_amdgcn_mfma_f32_32x32x16_f16(wr0, aS[cur][ks*2+0], accR, 0, 0, 0);
            accI = __builtin_amdgcn_mfma_f32_32x32x16_f16(wi0, aS[cur][ks*2+0], accI, 0, 0, 0);
            accR = __builtin_amdgcn_mfma_f32_32x32x16_f16(wr1, aS[cur][ks*2+1], accR, 0, 0, 0);
            accI = __builtin_amdgcn_mfma_f32_32x32x16_f16(wi1, aS[cur][ks*2+1], accI, 0, 0, 0);
        }
        if (s < 7) __syncthreads();
    }

    // ---- epilogue (phasor-product): lane = one output row; 16 h values.
    // Per term accumulate a=|zr|, c=s*zi, and the complex product of
    // w = 1 + e^{-2a}(cos 2c, -sin 2c). ONE log + ONE atan2 per 16 terms:
    //   sum lr = sum a - 16*LOG2 + 0.5*log|P|^2      (exact)
    //   sum li = sum c + angle(P)                    (exact mod 2pi)
    // Winding (2pi*k) is invisible: partials are summed then consumed by
    // sincos in lse_final; mode-1 oim is a principal-value atan2 of sums.
    const int hbase = hs * 32 + 4 * half;
    float Apos = 0.f, Cpos = 0.f, Aneg = 0.f, Cneg = 0.f;
    float Ppr = 1.f, Ppi = 0.f, Pnr = 1.f, Pni = 0.f;
    #pragma unroll
    for (int reg = 0; reg < 16; reg++) {
        int h = hbase + (reg & 3) + 8 * (reg >> 2);
        float brv = br[h], biv = bi[h];
        float tr = accR[reg];
        float ti = accI[reg];
        // pos: z = (tr+brv) + i(ti+biv)
        {
            float zr = tr + brv, zi = ti + biv;
            float s = (zr < 0.0f) ? -1.0f : 1.0f;
            float a = zr * s, c = zi * s;
            float e = __expf(-2.0f * a);
            float s2, c2; __sincosf(2.0f * c, &s2, &c2);
            float wre = fmaf(e, c2, 1.0f);
            float wim = -e * s2;
            Apos += a; Cpos += c;
            float t0 = Ppr * wre - Ppi * wim;
            Ppi = fmaf(Ppr, wim, Ppi * wre);
            Ppr = t0;
        }
        // neg: z = (brv-tr) + i(biv-ti)
        {
            float zr = brv - tr, zi = biv - ti;
            float s = (zr < 0.0f) ? -1.0f : 1.0f;
            float a = zr * s, c = zi * s;
            float e = __expf(-2.0f * a);
            float s2, c2; __sincosf(2.0f * c, &s2, &c2);
            float wre = fmaf(e, c2, 1.0f);
            float wim = -e * s2;
            Aneg += a; Cneg += c;
            float t0 = Pnr * wre - Pni * wim;
            Pni = fmaf(Pnr, wim, Pni * wre);
            Pnr = t0;
        }
    }
    float pr = Apos - 16.0f * LOG2C
             + 0.5f * __logf(fmaf(Ppr, Ppr, Ppi * Ppi));
    float pi = Cpos + atan2_full(Ppi, Ppr);
    float nr = Aneg - 16.0f * LOG2C
             + 0.5f * __logf(fmaf(Pnr, Pnr, Pni * Pni));
    float ni = Cneg + atan2_full(Pni, Pnr);

    pr += __shfl_xor(pr, 32, 64);
    pi += __shfl_xor(pi, 32, 64);
    nr += __shfl_xor(nr, 32, 64);
    ni += __shfl_xor(ni, 32, 64);
    if (half == 0) {
        // coalesced: 32 lanes write 512B; each (hs,row) written exactly once
        part[(size_t)hs * M_ + m0 + c32] = make_float4(pr, pi, nr, ni);
    }
}

// --- reduce the 128 h-slice partials per row ---
__global__ __launch_bounds__(64) void reduce_hb(
    const float4* __restrict__ part, float4* __restrict__ red)
{
    int row = blockIdx.x * 64 + threadIdx.x;
    float a0 = 0.f, a1 = 0.f, a2 = 0.f, a3 = 0.f;
    #pragma unroll 8
    for (int hb = 0; hb < NHB2_; hb++) {
        float4 v = part[(size_t)hb * M_ + row];
        a0 += v.x; a1 += v.y; a2 += v.z; a3 += v.w;
    }
    red[row] = make_float4(a0, a1, a2, a3);
}

// --- final logsumexp over 32 complex values per batch element ---
__global__ __launch_bounds__(64) void lse_final(
    const float4* __restrict__ red, float* __restrict__ out, int mode)
{
    int b = blockIdx.x * 64 + threadIdx.x;
    float re[32], im[32];
    #pragma unroll
    for (int t = 0; t < T_; t++) {
        float4 v = red[t * B_ + b];
        re[t]      = v.x; im[t]      = v.y;
        re[16 + t] = v.z; im[16 + t] = v.w;
    }
    float m = re[0];
    #pragma unroll
    for (int k = 1; k < 32; k++) m = fmaxf(m, re[k]);
    float Sr = 0.f, Si = 0.f;
    #pragma unroll
    for (int k = 0; k < 32; k++) {
        float mag = expf(re[k] - m);
        float s, c;
        sincosf(im[k], &s, &c);   // |im| can be tens of rad: libm reduction
        Sr = fmaf(mag, c, Sr);
        Si = fmaf(mag, s, Si);
    }
    float ore = 0.5f * logf(fmaf(Sr, Sr, Si * Si)) + m;
    float oim = atan2f(Si, Sr);
    if (mode == 0) out[b] = ore;
    else { out[b] = ore; out[B_ + b] = oim; }
}

// =======================================================================
// FALLBACK PATH — round-4 fp32 kernels (verified passing), used only if
// ws_size is too small for the packs.
// =======================================================================
#define FBM 128
#define FBH 64
#define FHC 4
#define FHBG (H_/(FBH*FHC))
#define FBK 16
#define FASTR 132
#define FPS (FHBG*M_)

__global__ __launch_bounds__(256, 3) void gemm_epi_fb(
    const float* __restrict__ x, const int* __restrict__ trans,
    const float* __restrict__ Wr, const float* __restrict__ Wi,
    const float* __restrict__ br, const float* __restrict__ bi,
    float* __restrict__ part)
{
    __shared__ float As[FBK * FASTR];
    __shared__ float Brs[FBK * FBH];
    __shared__ float Bis[FBK * FBH];

    const int tid = threadIdx.x;
    const int tx = tid & 15;
    const int ty = tid >> 4;
    const int hbg = blockIdx.x;
    const int m0 = blockIdx.y * FBM;
    const int t_band = m0 >> 10;
    const int* __restrict__ trow = trans + t_band * N_;

    float pr[8] = {}, pi[8] = {}, nr[8] = {}, ni[8] = {};

    for (int hc = 0; hc < FHC; hc++) {
        const int h0 = (hbg * FHC + hc) * FBH;
        float accre[8][4] = {}, accim[8][4] = {};
        for (int k0 = 0; k0 < N_; k0 += FBK) {
            #pragma unroll
            for (int p = 0; p < 8; p++) {
                int idx = tid + p * 256;
                int kk = idx & 15, r = idx >> 4;
                int b = (m0 + r) & (B_ - 1);
                As[kk * FASTR + r] = x[(size_t)b * N_ + trow[k0 + kk]];
            }
            {
                int r = tid >> 4, c4 = tid & 15;
                *(float4*)(Brs + r * FBH + c4 * 4) =
                    *(const float4*)(Wr + (size_t)(k0 + r) * H_ + h0 + c4 * 4);
                *(float4*)(Bis + r * FBH + c4 * 4) =
                    *(const float4*)(Wi + (size_t)(k0 + r) * H_ + h0 + c4 * 4);
            }
            __syncthreads();
            #pragma unroll
            for (int k = 0; k < FBK; k++) {
                float a[8], wr[4], wi[4];
                *(float4*)&a[0]  = *(float4*)&As[k * FASTR + ty * 8];
                *(float4*)&a[4]  = *(float4*)&As[k * FASTR + ty * 8 + 4];
                *(float4*)&wr[0] = *(float4*)&Brs[k * FBH + tx * 4];
                *(float4*)&wi[0] = *(float4*)&Bis[k * FBH + tx * 4];
                #pragma unroll
                for (int i = 0; i < 8; i++)
                    #pragma unroll
                    for (int j = 0; j < 4; j++) {
                        accre[i][j] = fmaf(a[i], wr[j], accre[i][j]);
                        accim[i][j] = fmaf(a[i], wi[j], accim[i][j]);
                    }
            }
            __syncthreads();
        }
        float brv[4], biv[4];
        #pragma unroll
        for (int j = 0; j < 4; j++) {
            brv[j] = br[h0 + tx * 4 + j];
            biv[j] = bi[h0 + tx * 4 + j];
        }
        #pragma unroll
        for (int i = 0; i < 8; i++)
            #pragma unroll
            for (int j = 0; j < 4; j++) {
                float tr = accre[i][j], ti = accim[i][j];
                float lr, li;
                log_cosh_c(tr + brv[j], ti + biv[j], lr, li);
                pr[i] += lr; pi[i] += li;
                log_cosh_c(brv[j] - tr, biv[j] - ti, lr, li);
                nr[i] += lr; ni[i] += li;
            }
    }
    #pragma unroll
    for (int i = 0; i < 8; i++) {
        float a0 = pr[i], a1 = pi[i], a2 = nr[i], a3 = ni[i];
        #pragma unroll
        for (int off = 1; off < 16; off <<= 1) {
            a0 += __shfl_xor(a0, off, 64);
            a1 += __shfl_xor(a1, off, 64);
            a2 += __shfl_xor(a2, off, 64);
            a3 += __shfl_xor(a3, off, 64);
        }
        if (tx == 0) {
            int row = m0 + ty * 8 + i;
            part[0 * FPS + hbg * M_ + row] = a0;
            part[1 * FPS + hbg * M_ + row] = a1;
            part[2 * FPS + hbg * M_ + row] = a2;
            part[3 * FPS + hbg * M_ + row] = a3;
        }
    }
}

__global__ __launch_bounds__(256) void sum_lse_fb(
    const float* __restrict__ part, float* __restrict__ out, int mode)
{
    int b = blockIdx.x * 256 + threadIdx.x;
    float re[32], im[32];
    #pragma unroll
    for (int t = 0; t < T_; t++) {
        int row = t * B_ + b;
        float a0 = 0.f, a1 = 0.f, a2 = 0.f, a3 = 0.f;
        for (int hb = 0; hb < FHBG; hb++) {
            a0 += part[0 * FPS + hb * M_ + row];
            a1 += part[1 * FPS + hb * M_ + row];
            a2 += part[2 * FPS + hb * M_ + row];
            a3 += part[3 * FPS + hb * M_ + row];
        }
        re[t]      = a0; im[t]      = a1;
        re[16 + t] = a2; im[16 + t] = a3;
    }
    float m = re[0];
    #pragma unroll
    for (int k = 1; k < 32; k++) m = fmaxf(m, re[k]);
    float Sr = 0.f, Si = 0.f;
    #pragma unroll
    for (int k = 0; k < 32; k++) {
        float mag = expf(re[k] - m);
        float s, c;
        sincosf(im[k], &s, &c);
        Sr = fmaf(mag, c, Sr);
        Si = fmaf(mag, s, Si);
    }
    float ore = 0.5f * logf(fmaf(Sr, Sr, Si * Si)) + m;
    float oim = atan2f(Si, Sr);
    if (mode == 0) out[b] = ore;
    else { out[b] = ore; out[B_ + b] = oim; }
}

// =======================================================================

extern "C" void kernel_launch(void* const* d_in, const int* in_sizes, int n_in,
                              void* d_out, int out_size, void* d_ws, size_t ws_size,
                              hipStream_t stream) {
    const float *x = nullptr, *Wr = nullptr, *Wi = nullptr, *br = nullptr, *bi = nullptr;
    const int *trans = nullptr;
    for (int i = 0; i < n_in; i++) {
        int s = in_sizes[i];
        if (s == B_ * N_ && !x)            x  = (const float*)d_in[i];
        else if (s == N_ * H_)             { if (!Wr) Wr = (const float*)d_in[i];
                                             else if (!Wi) Wi = (const float*)d_in[i]; }
        else if (s == H_)                  { if (!br) br = (const float*)d_in[i];
                                             else if (!bi) bi = (const float*)d_in[i]; }
        else if (s == T_ * N_ && !trans)   trans = (const int*)d_in[i];
    }
    if (!x)     x     = (const float*)d_in[0];
    if (!Wr)    Wr    = (const float*)d_in[1];
    if (!Wi)    Wi    = (const float*)d_in[2];
    if (!br)    br    = (const float*)d_in[3];
    if (!bi)    bi    = (const float*)d_in[4];
    if (!trans) trans = (const int*)d_in[5];

    float* out = (float*)d_out;
    const int mode = (out_size == B_) ? 0 : 1;

    const size_t NEED = (size_t)2 * M_ * N_          // A16 (f16)
                      + (size_t)4 * N_ * H_          // Wr16+Wi16 (f16)
                      + (size_t)NHB2_ * M_ * 16      // float4 partials
                      + (size_t)M_ * 16;             // float4 reduced

    if (ws_size >= NEED) {
        signed char* A16  = (signed char*)d_ws;
        signed char* Wr16 = A16  + (size_t)2 * M_ * N_;
        signed char* Wi16 = Wr16 + (size_t)2 * N_ * H_;
        float4* part = (float4*)(Wi16 + (size_t)2 * N_ * H_);
        float4* red  = part + (size_t)NHB2_ * M_;

        prep_A16<<<(M_ * (N_ / 8)) / 256, 256, 0, stream>>>(x, trans, A16);
        dim3 gw((N_ / 8) * H_ / 256, 2);
        prep_W16<<<gw, 256, 0, stream>>>(Wr, Wi, Wr16, Wi16);
        gemm_f16<<<128 * 128, 256, 0, stream>>>(A16, Wr16, Wi16,
                                                br, bi, part);
        reduce_hb<<<M_ / 64, 64, 0, stream>>>(part, red);
        lse_final<<<B_ / 64, 64, 0, stream>>>(red, out, mode);
    } else {
        float* part = (float*)d_ws;
        dim3 grid(FHBG, M_ / FBM);
        gemm_epi_fb<<<grid, 256, 0, stream>>>(x, trans, Wr, Wi, br, bi, part);
        sum_lse_fb<<<B_ / 256, 256, 0, stream>>>(part, out, mode);
    }
}

// Round 13
// 511.688 us; speedup vs baseline: 1.1737x; 1.0479x over previous
//
#include <hip/hip_runtime.h>
#include <math.h>

// Problem constants (fixed by setup_inputs)
#define B_ 1024
#define N_ 1024      // K dimension of the GEMM
#define T_ 16
#define H_ 4096
#define M_ (T_*B_)   // 16384 rows, row = t*B_ + b
#define NHB2_ 128    // h-slices of 32

#define LOG2C 0.69314718055994530942f

typedef int      i32x4  __attribute__((ext_vector_type(4)));
typedef _Float16 f16x8  __attribute__((ext_vector_type(8)));
typedef float    f32x16 __attribute__((ext_vector_type(16)));

// ---------------- numerics helpers ----------------

// full-range fast atan2 (deg-11 odd minimax, reciprocal range reduction).
// |err| ~1e-5. Used ONCE per 16-term phasor product (not per term), so the
// approximation error contribution is 16x smaller than the old per-term use.
__device__ __forceinline__ float atan2_full(float y, float x) {
    float ax = fabsf(x), ay = fabsf(y);
    float mn = fminf(ay, ax), mx = fmaxf(ay, ax);
    float r  = __fdividef(mn, mx);        // in [0,1]
    float t  = r * r;
    float p  = fmaf(t, -0.0117212f, 0.05265332f);
    p = fmaf(t, p, -0.11643287f);
    p = fmaf(t, p,  0.19354346f);
    p = fmaf(t, p, -0.33262347f);
    p = fmaf(t, p,  0.99997726f);
    float a = r * p;
    a = (ay > ax) ? (1.5707963267948966f - a) : a;
    a = (x < 0.0f) ? (3.14159265358979323846f - a) : a;
    return (y < 0.0f) ? -a : a;
}

// fallback-path log_cosh (libm atan2)
__device__ __forceinline__ void log_cosh_c(float zr, float zi, float& lr, float& li) {
    float s = (zr < 0.0f) ? -1.0f : 1.0f;
    float a = zr * s;
    float c = zi * s;
    float e = __expf(-2.0f * a);
    float s2, c2;
    __sincosf(2.0f * c, &s2, &c2);
    float wre = fmaf(e, c2, 1.0f);
    float wim = -e * s2;
    float mag2 = fmaf(wre, wre, wim * wim);
    lr = a + 0.5f * __logf(mag2) - LOG2C;
    li = c + atan2f(wim, wre);
}

__device__ __forceinline__ void gll16(const void* g, void* l) {
    __builtin_amdgcn_global_load_lds(
        (const __attribute__((address_space(1))) unsigned int*)g,
        (__attribute__((address_space(3))) unsigned int*)l,
        16, 0, 0);
}

// =======================================================================
// FAST PATH (f16 MFMA, W-through-LDS hybrid GEMM, PHASOR-PRODUCT epilogue,
// 4 blocks/CU).
// r25 post-mortem of r24 (phasor epilogue WIN): gemm 419->377 us, VALU
// 78->51.5, MfmaUtil 41.3, VGPR 48, no spill. Pipe accounting at 377 us:
// MFMA floor ~110 us-eq, LDS ~164, epilogue VALU ~185; VALU+MFMA = 92%
// combined issue but nothing saturated individually -> latency/overlap
// residual at 13.4 waves/CU (the (256,3) cap). Register headroom is big:
// 48 arch + 32 AGPR = 80 unified << 128.
// This round: ONE variable -- __launch_bounds__(256,4): 4 blocks/CU =
// 16 waves/CU. LDS 4x32=128<=160 KB ok; regs 80<=128 ok (48 spare for the
// compiler's A-prefetch hoisting). +33% TLP attacks the overlap residual.
// Zero computation change => bitwise-identical result (absmax 0.125).
// Guards: WRITE ~33 MB, VGPR<=~96, occupancy ~50-55%.
// ws layout (bytes):
//   A16  [K/8][M] 16B chunks (8 f16 of consecutive k)   33.55 MB
//   Wr16,Wi16 [K/8][H] 16B chunks (f16, W^T)            2 x 8.39 MB
//   part float4[128][M]  33.55 MB ;  red float4[M]  0.26 MB
// =======================================================================

// --- prep A: gather + f16 convert. One thread = one 16B chunk (8 elems).
__global__ __launch_bounds__(256) void prep_A16(
    const float* __restrict__ x, const int* __restrict__ trans,
    signed char* __restrict__ A16)
{
    int ci = blockIdx.x * 256 + threadIdx.x;   // kc*M_ + row, kc in 0..127
    int row = ci & (M_ - 1);
    int kc  = ci >> 14;
    int t   = row >> 10, b = row & (B_ - 1);
    const int* __restrict__ trow = trans + t * N_ + kc * 8;
    const float* __restrict__ xr = x + (size_t)b * N_;
    alignas(16) _Float16 buf[8];
    #pragma unroll
    for (int j = 0; j < 8; j++) buf[j] = (_Float16)xr[trow[j]];
    *(uint4*)(A16 + (size_t)ci * 16) = *(uint4*)buf;
}

// --- prep W: transpose-pack + f16 convert. blockIdx.y: 0->Wr, 1->Wi.
__global__ __launch_bounds__(256) void prep_W16(
    const float* __restrict__ Wr, const float* __restrict__ Wi,
    signed char* __restrict__ Wr16, signed char* __restrict__ Wi16)
{
    int ci = blockIdx.x * 256 + threadIdx.x;   // kc*H_ + h, kc in 0..127
    int h  = ci & (H_ - 1);
    int kc = ci >> 12;
    const float* __restrict__ W = blockIdx.y ? Wi : Wr;
    signed char* __restrict__ D = blockIdx.y ? Wi16 : Wr16;
    alignas(16) _Float16 buf[8];
    #pragma unroll
    for (int j = 0; j < 8; j++)
        buf[j] = (_Float16)W[(size_t)(kc * 8 + j) * H_ + h];
    *(uint4*)(D + (size_t)ci * 16) = *(uint4*)buf;
}

// --- main f16 MFMA GEMM: W double-buffered through LDS, A batch-prefetched.
// Structure (== r20/r24 skeleton): block = 4 waves x 32 rows = 128 rows
// x one 32-h slice; W staged into 2 x 16 KB LDS buffers per K=128 band
// (8 bands, 8 barriers; prefetch for band s+1 issued at TOP of band s so
// the barrier's vmcnt(0) drain is ~aged-out); A streams global->VGPR in
// per-band batches of 8 chunk loads (compiler collapses the slots: VGPR 48).
// MFMA operands SWAPPED (A-op = W, B-op = xt): D[h(regs)][m(cols)] -- the
// h-reduction is in-lane adds + ONE shuffle; partial write is coalesced.
// Layouts (dtype-independent, HW-verified r8-24): A/B frag lane l holds
// 16B chunk k8=(l>>5), index (l&31); C/D col=lane&31,
// row=(reg&3)+8*(reg>>2)+4*(lane>>5) [m74/m101].
__global__ __launch_bounds__(256, 4) void gemm_f16(
    const signed char* __restrict__ A16,
    const signed char* __restrict__ Wr16, const signed char* __restrict__ Wi16,
    const float* __restrict__ br, const float* __restrict__ bi,
    float4* __restrict__ part)
{
    // [buf(2)][arr(2)][q(16)][h(32)] 16B chunks
    __shared__ __align__(16) signed char sW[32768];

    const int tid  = threadIdx.x;
    const int l    = tid & 63;
    const int w    = tid >> 6;
    const int c32  = l & 31;
    const int half = l >> 5;
    const int bx   = blockIdx.x;
    const int hs   = bx & 127;       // 0..127  h-slice (fastest-varying)
    const int mb   = bx >> 7;        // 0..127  m-block (mb-major: A L2-hot,
                                     //  W co-streamed from L3 by the group)
    const int m0   = mb * 128 + w * 32;   // wave's 32-row tile
    const int rowA = m0 + c32;

    // A chunk pointer: slot p holds chunk band*16 + 2p + half, row rowA
    const signed char* pA = A16 + ((size_t)half * M_ + rowA) * 16;
    const size_t strA = (size_t)2 * M_ * 16;   // advance 2 k8-chunks

    const int q_lo = tid >> 5;      // 0..7 (staging k-chunk low bits)
    const int h_st = tid & 31;      // staging h index
    const size_t woff = ((size_t)q_lo * H_ + hs * 32 + h_st) * 16;
    const signed char* wsrc0 = Wr16 + woff;
    const signed char* wsrc1 = Wi16 + woff;
    const int ldst = tid * 16;      // LDS dest: uniform + lane*16
    const size_t WQ8 = (size_t)8 * H_ * 16;    // 8 k8-chunks of W

    f32x16 accR = {}, accI = {};

    // A slots: [band-parity][8], batch-loaded one band ahead
    f16x8 aS[2][8];

    // ---- prologue: band 0 A batch + band 0 W into buf 0
    #pragma unroll
    for (int p = 0; p < 8; p++) {
        aS[0][p] = *(const f16x8*)pA;  pA += strA;
    }
    gll16(wsrc0,       sW + 0 * 4096 + ldst);   // arr0 q0..7
    gll16(wsrc0 + WQ8, sW + 1 * 4096 + ldst);   // arr0 q8..15
    gll16(wsrc1,       sW + 2 * 4096 + ldst);   // arr1 q0..7
    gll16(wsrc1 + WQ8, sW + 3 * 4096 + ldst);   // arr1 q8..15
    __syncthreads();

    const int lbase = half * 512 + c32 * 16;    // per-lane LDS read base
    const size_t WBAND = (size_t)16 * H_ * 16;  // per-band W bytes per array

    #pragma unroll
    for (int s = 0; s < 8; s++) {
        const int cur = s & 1;
        const int nxt = cur ^ 1;

        // ---- prefetch band s+1 FIRST: 4 gll16 -> other LDS buffer, plus
        //      its 8 A chunk loads -> other slot set. By the band-end
        //      barrier these are ~4 ks old => vmcnt(0) drain ~free.
        if (s < 7) {
            size_t wadd = (size_t)(s + 1) * WBAND;
            gll16(wsrc0 + wadd,       sW + nxt * 16384 + 0 * 4096 + ldst);
            gll16(wsrc0 + wadd + WQ8, sW + nxt * 16384 + 1 * 4096 + ldst);
            gll16(wsrc1 + wadd,       sW + nxt * 16384 + 2 * 4096 + ldst);
            gll16(wsrc1 + wadd + WQ8, sW + nxt * 16384 + 3 * 4096 + ldst);
            #pragma unroll
            for (int p = 0; p < 8; p++) {
                aS[nxt][p] = *(const f16x8*)pA;  pA += strA;
            }
        }

        // ---- 4 k-steps (K=32 each) from buf[cur]
        #pragma unroll
        for (int ks = 0; ks < 4; ks++) {
            int off = cur * 16384 + ks * 2048 + lbase;   // q = ks*4 + 2j + half
            f16x8 wr0 = *(const f16x8*)&sW[off];                  // arr0 j0
            f16x8 wr1 = *(const f16x8*)&sW[off + 1024];           // arr0 j1
            f16x8 wi0 = *(const f16x8*)&sW[off + 8192];           // arr1 j0
            f16x8 wi1 = *(const f16x8*)&sW[off + 8192 + 1024];    // arr1 j1
            // swapped operands: D[h][m] += W^T[h][k] * xt[m][k]
            accR = __builtin_amdgcn_mfma_f32_32x32x16_f16(wr0, aS[cur][ks*2+0], accR, 0, 0, 0);
            accI = __builtin_amdgcn_mfma_f32_32x32x16_f16(wi0, aS[cur][ks*2+0], accI, 0, 0, 0);
            accR = __builtin_amdgcn_mfma_f32_32x32x16_f16(wr1, aS[cur][ks*2+1], accR, 0, 0, 0);
            accI = __builtin_amdgcn_mfma_f32_32x32x16_f16(wi1, aS[cur][ks*2+1], accI, 0, 0, 0);
        }
        if (s < 7) __syncthreads();
    }

    // ---- epilogue (phasor-product): lane = one output row; 16 h values.
    // Per term accumulate a=|zr|, c=s*zi, and the complex product of
    // w = 1 + e^{-2a}(cos 2c, -sin 2c). ONE log + ONE atan2 per 16 terms:
    //   sum lr = sum a - 16*LOG2 + 0.5*log|P|^2      (exact)
    //   sum li = sum c + angle(P)                    (exact mod 2pi)
    // Winding (2pi*k) is invisible: partials are summed then consumed by
    // sincos in lse_final; mode-1 oim is principal-value atan2 of sums.
    const int hbase = hs * 32 + 4 * half;
    float Apos = 0.f, Cpos = 0.f, Aneg = 0.f, Cneg = 0.f;
    float Ppr = 1.f, Ppi = 0.f, Pnr = 1.f, Pni = 0.f;
    #pragma unroll
    for (int reg = 0; reg < 16; reg++) {
        int h = hbase + (reg & 3) + 8 * (reg >> 2);
        float brv = br[h], biv = bi[h];
        float tr = accR[reg];
        float ti = accI[reg];
        // pos: z = (tr+brv) + i(ti+biv)
        {
            float zr = tr + brv, zi = ti + biv;
            float s = (zr < 0.0f) ? -1.0f : 1.0f;
            float a = zr * s, c = zi * s;
            float e = __expf(-2.0f * a);
            float s2, c2; __sincosf(2.0f * c, &s2, &c2);
            float wre = fmaf(e, c2, 1.0f);
            float wim = -e * s2;
            Apos += a; Cpos += c;
            float t0 = Ppr * wre - Ppi * wim;
            Ppi = fmaf(Ppr, wim, Ppi * wre);
            Ppr = t0;
        }
        // neg: z = (brv-tr) + i(biv-ti)
        {
            float zr = brv - tr, zi = biv - ti;
            float s = (zr < 0.0f) ? -1.0f : 1.0f;
            float a = zr * s, c = zi * s;
            float e = __expf(-2.0f * a);
            float s2, c2; __sincosf(2.0f * c, &s2, &c2);
            float wre = fmaf(e, c2, 1.0f);
            float wim = -e * s2;
            Aneg += a; Cneg += c;
            float t0 = Pnr * wre - Pni * wim;
            Pni = fmaf(Pnr, wim, Pni * wre);
            Pnr = t0;
        }
    }
    float pr = Apos - 16.0f * LOG2C
             + 0.5f * __logf(fmaf(Ppr, Ppr, Ppi * Ppi));
    float pi = Cpos + atan2_full(Ppi, Ppr);
    float nr = Aneg - 16.0f * LOG2C
             + 0.5f * __logf(fmaf(Pnr, Pnr, Pni * Pni));
    float ni = Cneg + atan2_full(Pni, Pnr);

    pr += __shfl_xor(pr, 32, 64);
    pi += __shfl_xor(pi, 32, 64);
    nr += __shfl_xor(nr, 32, 64);
    ni += __shfl_xor(ni, 32, 64);
    if (half == 0) {
        // coalesced: 32 lanes write 512B; each (hs,row) written exactly once
        part[(size_t)hs * M_ + m0 + c32] = make_float4(pr, pi, nr, ni);
    }
}

// --- reduce the 128 h-slice partials per row ---
__global__ __launch_bounds__(64) void reduce_hb(
    const float4* __restrict__ part, float4* __restrict__ red)
{
    int row = blockIdx.x * 64 + threadIdx.x;
    float a0 = 0.f, a1 = 0.f, a2 = 0.f, a3 = 0.f;
    #pragma unroll 8
    for (int hb = 0; hb < NHB2_; hb++) {
        float4 v = part[(size_t)hb * M_ + row];
        a0 += v.x; a1 += v.y; a2 += v.z; a3 += v.w;
    }
    red[row] = make_float4(a0, a1, a2, a3);
}

// --- final logsumexp over 32 complex values per batch element ---
__global__ __launch_bounds__(64) void lse_final(
    const float4* __restrict__ red, float* __restrict__ out, int mode)
{
    int b = blockIdx.x * 64 + threadIdx.x;
    float re[32], im[32];
    #pragma unroll
    for (int t = 0; t < T_; t++) {
        float4 v = red[t * B_ + b];
        re[t]      = v.x; im[t]      = v.y;
        re[16 + t] = v.z; im[16 + t] = v.w;
    }
    float m = re[0];
    #pragma unroll
    for (int k = 1; k < 32; k++) m = fmaxf(m, re[k]);
    float Sr = 0.f, Si = 0.f;
    #pragma unroll
    for (int k = 0; k < 32; k++) {
        float mag = expf(re[k] - m);
        float s, c;
        sincosf(im[k], &s, &c);   // |im| can be tens of rad: libm reduction
        Sr = fmaf(mag, c, Sr);
        Si = fmaf(mag, s, Si);
    }
    float ore = 0.5f * logf(fmaf(Sr, Sr, Si * Si)) + m;
    float oim = atan2f(Si, Sr);
    if (mode == 0) out[b] = ore;
    else { out[b] = ore; out[B_ + b] = oim; }
}

// =======================================================================
// FALLBACK PATH — round-4 fp32 kernels (verified passing), used only if
// ws_size is too small for the packs.
// =======================================================================
#define FBM 128
#define FBH 64
#define FHC 4
#define FHBG (H_/(FBH*FHC))
#define FBK 16
#define FASTR 132
#define FPS (FHBG*M_)

__global__ __launch_bounds__(256, 3) void gemm_epi_fb(
    const float* __restrict__ x, const int* __restrict__ trans,
    const float* __restrict__ Wr, const float* __restrict__ Wi,
    const float* __restrict__ br, const float* __restrict__ bi,
    float* __restrict__ part)
{
    __shared__ float As[FBK * FASTR];
    __shared__ float Brs[FBK * FBH];
    __shared__ float Bis[FBK * FBH];

    const int tid = threadIdx.x;
    const int tx = tid & 15;
    const int ty = tid >> 4;
    const int hbg = blockIdx.x;
    const int m0 = blockIdx.y * FBM;
    const int t_band = m0 >> 10;
    const int* __restrict__ trow = trans + t_band * N_;

    float pr[8] = {}, pi[8] = {}, nr[8] = {}, ni[8] = {};

    for (int hc = 0; hc < FHC; hc++) {
        const int h0 = (hbg * FHC + hc) * FBH;
        float accre[8][4] = {}, accim[8][4] = {};
        for (int k0 = 0; k0 < N_; k0 += FBK) {
            #pragma unroll
            for (int p = 0; p < 8; p++) {
                int idx = tid + p * 256;
                int kk = idx & 15, r = idx >> 4;
                int b = (m0 + r) & (B_ - 1);
                As[kk * FASTR + r] = x[(size_t)b * N_ + trow[k0 + kk]];
            }
            {
                int r = tid >> 4, c4 = tid & 15;
                *(float4*)(Brs + r * FBH + c4 * 4) =
                    *(const float4*)(Wr + (size_t)(k0 + r) * H_ + h0 + c4 * 4);
                *(float4*)(Bis + r * FBH + c4 * 4) =
                    *(const float4*)(Wi + (size_t)(k0 + r) * H_ + h0 + c4 * 4);
            }
            __syncthreads();
            #pragma unroll
            for (int k = 0; k < FBK; k++) {
                float a[8], wr[4], wi[4];
                *(float4*)&a[0]  = *(float4*)&As[k * FASTR + ty * 8];
                *(float4*)&a[4]  = *(float4*)&As[k * FASTR + ty * 8 + 4];
                *(float4*)&wr[0] = *(float4*)&Brs[k * FBH + tx * 4];
                *(float4*)&wi[0] = *(float4*)&Bis[k * FBH + tx * 4];
                #pragma unroll
                for (int i = 0; i < 8; i++)
                    #pragma unroll
                    for (int j = 0; j < 4; j++) {
                        accre[i][j] = fmaf(a[i], wr[j], accre[i][j]);
                        accim[i][j] = fmaf(a[i], wi[j], accim[i][j]);
                    }
            }
            __syncthreads();
        }
        float brv[4], biv[4];
        #pragma unroll
        for (int j = 0; j < 4; j++) {
            brv[j] = br[h0 + tx * 4 + j];
            biv[j] = bi[h0 + tx * 4 + j];
        }
        #pragma unroll
        for (int i = 0; i < 8; i++)
            #pragma unroll
            for (int j = 0; j < 4; j++) {
                float tr = accre[i][j], ti = accim[i][j];
                float lr, li;
                log_cosh_c(tr + brv[j], ti + biv[j], lr, li);
                pr[i] += lr; pi[i] += li;
                log_cosh_c(brv[j] - tr, biv[j] - ti, lr, li);
                nr[i] += lr; ni[i] += li;
            }
    }
    #pragma unroll
    for (int i = 0; i < 8; i++) {
        float a0 = pr[i], a1 = pi[i], a2 = nr[i], a3 = ni[i];
        #pragma unroll
        for (int off = 1; off < 16; off <<= 1) {
            a0 += __shfl_xor(a0, off, 64);
            a1 += __shfl_xor(a1, off, 64);
            a2 += __shfl_xor(a2, off, 64);
            a3 += __shfl_xor(a3, off, 64);
        }
        if (tx == 0) {
            int row = m0 + ty * 8 + i;
            part[0 * FPS + hbg * M_ + row] = a0;
            part[1 * FPS + hbg * M_ + row] = a1;
            part[2 * FPS + hbg * M_ + row] = a2;
            part[3 * FPS + hbg * M_ + row] = a3;
        }
    }
}

__global__ __launch_bounds__(256) void sum_lse_fb(
    const float* __restrict__ part, float* __restrict__ out, int mode)
{
    int b = blockIdx.x * 256 + threadIdx.x;
    float re[32], im[32];
    #pragma unroll
    for (int t = 0; t < T_; t++) {
        int row = t * B_ + b;
        float a0 = 0.f, a1 = 0.f, a2 = 0.f, a3 = 0.f;
        for (int hb = 0; hb < FHBG; hb++) {
            a0 += part[0 * FPS + hb * M_ + row];
            a1 += part[1 * FPS + hb * M_ + row];
            a2 += part[2 * FPS + hb * M_ + row];
            a3 += part[3 * FPS + hb * M_ + row];
        }
        re[t]      = a0; im[t]      = a1;
        re[16 + t] = a2; im[16 + t] = a3;
    }
    float m = re[0];
    #pragma unroll
    for (int k = 1; k < 32; k++) m = fmaxf(m, re[k]);
    float Sr = 0.f, Si = 0.f;
    #pragma unroll
    for (int k = 0; k < 32; k++) {
        float mag = expf(re[k] - m);
        float s, c;
        sincosf(im[k], &s, &c);
        Sr = fmaf(mag, c, Sr);
        Si = fmaf(mag, s, Si);
    }
    float ore = 0.5f * logf(fmaf(Sr, Sr, Si * Si)) + m;
    float oim = atan2f(Si, Sr);
    if (mode == 0) out[b] = ore;
    else { out[b] = ore; out[B_ + b] = oim; }
}

// =======================================================================

extern "C" void kernel_launch(void* const* d_in, const int* in_sizes, int n_in,
                              void* d_out, int out_size, void* d_ws, size_t ws_size,
                              hipStream_t stream) {
    const float *x = nullptr, *Wr = nullptr, *Wi = nullptr, *br = nullptr, *bi = nullptr;
    const int *trans = nullptr;
    for (int i = 0; i < n_in; i++) {
        int s = in_sizes[i];
        if (s == B_ * N_ && !x)            x  = (const float*)d_in[i];
        else if (s == N_ * H_)             { if (!Wr) Wr = (const float*)d_in[i];
                                             else if (!Wi) Wi = (const float*)d_in[i]; }
        else if (s == H_)                  { if (!br) br = (const float*)d_in[i];
                                             else if (!bi) bi = (const float*)d_in[i]; }
        else if (s == T_ * N_ && !trans)   trans = (const int*)d_in[i];
    }
    if (!x)     x     = (const float*)d_in[0];
    if (!Wr)    Wr    = (const float*)d_in[1];
    if (!Wi)    Wi    = (const float*)d_in[2];
    if (!br)    br    = (const float*)d_in[3];
    if (!bi)    bi    = (const float*)d_in[4];
    if (!trans) trans = (const int*)d_in[5];

    float* out = (float*)d_out;
    const int mode = (out_size == B_) ? 0 : 1;

    const size_t NEED = (size_t)2 * M_ * N_          // A16 (f16)
                      + (size_t)4 * N_ * H_          // Wr16+Wi16 (f16)
                      + (size_t)NHB2_ * M_ * 16      // float4 partials
                      + (size_t)M_ * 16;             // float4 reduced

    if (ws_size >= NEED) {
        signed char* A16  = (signed char*)d_ws;
        signed char* Wr16 = A16  + (size_t)2 * M_ * N_;
        signed char* Wi16 = Wr16 + (size_t)2 * N_ * H_;
        float4* part = (float4*)(Wi16 + (size_t)2 * N_ * H_);
        float4* red  = part + (size_t)NHB2_ * M_;

        prep_A16<<<(M_ * (N_ / 8)) / 256, 256, 0, stream>>>(x, trans, A16);
        dim3 gw((N_ / 8) * H_ / 256, 2);
        prep_W16<<<gw, 256, 0, stream>>>(Wr, Wi, Wr16, Wi16);
        gemm_f16<<<128 * 128, 256, 0, stream>>>(A16, Wr16, Wi16,
                                                br, bi, part);
        reduce_hb<<<M_ / 64, 64, 0, stream>>>(part, red);
        lse_final<<<B_ / 64, 64, 0, stream>>>(red, out, mode);
    } else {
        float* part = (float*)d_ws;
        dim3 grid(FHBG, M_ / FBM);
        gemm_epi_fb<<<grid, 256, 0, stream>>>(x, trans, Wr, Wi, br, bi, part);
        sum_lse_fb<<<B_ / 256, 256, 0, stream>>>(part, out, mode);
    }
}

// Round 16
// 451.256 us; speedup vs baseline: 1.3309x; 1.1339x over previous
//
#include <hip/hip_runtime.h>
#include <math.h>

// Problem constants (fixed by setup_inputs)
#define B_ 1024
#define N_ 1024      // K dimension of the GEMM
#define T_ 16
#define H_ 4096
#define M_ (T_*B_)   // 16384 rows, row = t*B_ + b
#define NHB2_ 128    // h-slices of 32

#define LOG2C 0.69314718055994530942f

typedef int      i32x4  __attribute__((ext_vector_type(4)));
typedef _Float16 f16x8  __attribute__((ext_vector_type(8)));
typedef float    f32x16 __attribute__((ext_vector_type(16)));

// ---------------- numerics helpers ----------------

// full-range fast atan2 (deg-11 odd minimax, reciprocal range reduction).
// |err| ~1e-5. Used ONCE per 16-term phasor product (not per term), so the
// approximation error contribution is 16x smaller than the old per-term use.
__device__ __forceinline__ float atan2_full(float y, float x) {
    float ax = fabsf(x), ay = fabsf(y);
    float mn = fminf(ay, ax), mx = fmaxf(ay, ax);
    float r  = __fdividef(mn, mx);        // in [0,1]
    float t  = r * r;
    float p  = fmaf(t, -0.0117212f, 0.05265332f);
    p = fmaf(t, p, -0.11643287f);
    p = fmaf(t, p,  0.19354346f);
    p = fmaf(t, p, -0.33262347f);
    p = fmaf(t, p,  0.99997726f);
    float a = r * p;
    a = (ay > ax) ? (1.5707963267948966f - a) : a;
    a = (x < 0.0f) ? (3.14159265358979323846f - a) : a;
    return (y < 0.0f) ? -a : a;
}

// fallback-path log_cosh (libm atan2)
__device__ __forceinline__ void log_cosh_c(float zr, float zi, float& lr, float& li) {
    float s = (zr < 0.0f) ? -1.0f : 1.0f;
    float a = zr * s;
    float c = zi * s;
    float e = __expf(-2.0f * a);
    float s2, c2;
    __sincosf(2.0f * c, &s2, &c2);
    float wre = fmaf(e, c2, 1.0f);
    float wim = -e * s2;
    float mag2 = fmaf(wre, wre, wim * wim);
    lr = a + 0.5f * __logf(mag2) - LOG2C;
    li = c + atan2f(wim, wre);
}

__device__ __forceinline__ void gll16(const void* g, void* l) {
    __builtin_amdgcn_global_load_lds(
        (const __attribute__((address_space(1))) unsigned int*)g,
        (__attribute__((address_space(3))) unsigned int*)l,
        16, 0, 0);
}

// =======================================================================
// FAST PATH (f16 MFMA, W-through-LDS hybrid GEMM, PHASOR-PRODUCT epilogue,
// 4 blocks/CU, LDS-GATHER prep_A).
// r28 == r27 resubmission (GPU broker timeout, no measurement).
// r27 post-mortem of r26 (CRASH, my bug): the LDS-gather prep_A16 had
// (a) wrong staging decomposition (rr=li>>6 assumed 64 float4/row; a
// 1024-float row is 256 float4 -> OOB LDS writes + OOB x reads) and
// (b) xs[16][1025] = 65,600 B > 64 KB static-shared limit.
// FIXED geometry: 8 rows/block -- xs[8][1025] = 32,800 B (fits, 2 blk/CU);
// staging rr=li>>8, cc=li&255 (8 iters/thread); grid (128,4). Phase 2:
// bb=tid&7 (row), q=tid>>3; 16 (t,kc) pairs/thread; gather stride 1025
// => the 8 lanes sharing an idx hit 8 distinct banks; writes are
// 8-lane-contiguous 128 B groups. Bounds: max row 127*8+7=1023 ok;
// 512 blocks x 4096 chunks = 128*M_ ok. Identical f32->f16 conversion
// per element => BITWISE-IDENTICAL A16 => absmax exactly 0.125.
// Rationale (r26): prep_A16's data-dependent gather (consecutive lanes
// share idx, stride-4KB -> 64 cache lines per load instr) dominates the
// 157 us non-gemm tail; LDS gather removes the coalescing penalty.
// Everything else byte-identical to the r13 measured build (512 us total,
// gemm 354 us @ MfmaUtil 42.6 / VALU 52.7 combined-issue plateau).
// ws layout (bytes):
//   A16  [K/8][M] 16B chunks (8 f16 of consecutive k)   33.55 MB
//   Wr16,Wi16 [K/8][H] 16B chunks (f16, W^T)            2 x 8.39 MB
//   part float4[128][M]  33.55 MB ;  red float4[M]  0.26 MB
// =======================================================================

// --- prep A: LDS-staged gather + f16 convert.
// grid (128, 4): blockIdx.x = 8-row group g; blockIdx.y = kc quarter.
// Phase 1: stage rows b = g*8..+7 into padded LDS (coalesced float4).
// Phase 2: thread (bb=tid&7, q=tid>>3) handles (t,kc) pairs p=q+32i,
//          gathers 8 values from LDS row bb, writes one 16B chunk each.
__global__ __launch_bounds__(256, 2) void prep_A16(
    const float* __restrict__ x, const int* __restrict__ trans,
    signed char* __restrict__ A16)
{
    __shared__ float xs[8][1025];    // odd stride: conflict-free gather
    const int tid = threadIdx.x;
    const int g   = blockIdx.x;      // row group: b = g*8 + bb
    const int kq  = blockIdx.y;      // kc quarter: kc = kq*32 + kcl

    // ---- stage 8 rows x 4 KB, coalesced float4 (2048 float4 / 256 thr)
    #pragma unroll
    for (int i = 0; i < 8; i++) {
        int li = i * 256 + tid;      // float4 index 0..2047
        int rr = li >> 8;            // row 0..7 (256 float4 per row)
        int cc = li & 255;           // float4 column 0..255
        float4 v = *(const float4*)(x + (size_t)(g * 8 + rr) * N_ + cc * 4);
        xs[rr][cc * 4 + 0] = v.x;
        xs[rr][cc * 4 + 1] = v.y;
        xs[rr][cc * 4 + 2] = v.z;
        xs[rr][cc * 4 + 3] = v.w;
    }
    __syncthreads();

    const int bb = tid & 7;
    const int q  = tid >> 3;         // 0..31
    #pragma unroll 4
    for (int i = 0; i < 16; i++) {
        int p  = q + (i << 5);       // 0..511 = 16 t x 32 kcl
        int t  = p >> 5;
        int kc = kq * 32 + (p & 31);
        const int* __restrict__ trow = trans + t * N_ + kc * 8;
        alignas(16) _Float16 buf[8];
        #pragma unroll
        for (int j = 0; j < 8; j++) buf[j] = (_Float16)xs[bb][trow[j]];
        size_t ci = (size_t)kc * M_ + t * B_ + g * 8 + bb;
        *(uint4*)(A16 + ci * 16) = *(uint4*)buf;
    }
}

// --- prep W: transpose-pack + f16 convert. blockIdx.y: 0->Wr, 1->Wi.
__global__ __launch_bounds__(256) void prep_W16(
    const float* __restrict__ Wr, const float* __restrict__ Wi,
    signed char* __restrict__ Wr16, signed char* __restrict__ Wi16)
{
    int ci = blockIdx.x * 256 + threadIdx.x;   // kc*H_ + h, kc in 0..127
    int h  = ci & (H_ - 1);
    int kc = ci >> 12;
    const float* __restrict__ W = blockIdx.y ? Wi : Wr;
    signed char* __restrict__ D = blockIdx.y ? Wi16 : Wr16;
    alignas(16) _Float16 buf[8];
    #pragma unroll
    for (int j = 0; j < 8; j++)
        buf[j] = (_Float16)W[(size_t)(kc * 8 + j) * H_ + h];
    *(uint4*)(D + (size_t)ci * 16) = *(uint4*)buf;
}

// --- main f16 MFMA GEMM: W double-buffered through LDS, A batch-prefetched.
// Structure (== r20/r24 skeleton, measured 354 us @ (256,4)): block =
// 4 waves x 32 rows = 128 rows x one 32-h slice; W staged into 2 x 16 KB
// LDS buffers per K=128 band (8 bands, 8 barriers; prefetch for band s+1
// issued at TOP of band s so the barrier's vmcnt(0) drain is ~aged-out);
// A streams global->VGPR in per-band batches of 8 chunk loads (compiler
// collapses the slots: VGPR 48).
// MFMA operands SWAPPED (A-op = W, B-op = xt): D[h(regs)][m(cols)] -- the
// h-reduction is in-lane adds + ONE shuffle; partial write is coalesced.
// Layouts (dtype-independent, HW-verified r8-25): A/B frag lane l holds
// 16B chunk k8=(l>>5), index (l&31); C/D col=lane&31,
// row=(reg&3)+8*(reg>>2)+4*(lane>>5) [m74/m101].
__global__ __launch_bounds__(256, 4) void gemm_f16(
    const signed char* __restrict__ A16,
    const signed char* __restrict__ Wr16, const signed char* __restrict__ Wi16,
    const float* __restrict__ br, const float* __restrict__ bi,
    float4* __restrict__ part)
{
    // [buf(2)][arr(2)][q(16)][h(32)] 16B chunks
    __shared__ __align__(16) signed char sW[32768];

    const int tid  = threadIdx.x;
    const int l    = tid & 63;
    const int w    = tid >> 6;
    const int c32  = l & 31;
    const int half = l >> 5;
    const int bx   = blockIdx.x;
    const int hs   = bx & 127;       // 0..127  h-slice (fastest-varying)
    const int mb   = bx >> 7;        // 0..127  m-block (mb-major: A L2-hot,
                                     //  W co-streamed from L3 by the group)
    const int m0   = mb * 128 + w * 32;   // wave's 32-row tile
    const int rowA = m0 + c32;

    // A chunk pointer: slot p holds chunk band*16 + 2p + half, row rowA
    const signed char* pA = A16 + ((size_t)half * M_ + rowA) * 16;
    const size_t strA = (size_t)2 * M_ * 16;   // advance 2 k8-chunks

    const int q_lo = tid >> 5;      // 0..7 (staging k-chunk low bits)
    const int h_st = tid & 31;      // staging h index
    const size_t woff = ((size_t)q_lo * H_ + hs * 32 + h_st) * 16;
    const signed char* wsrc0 = Wr16 + woff;
    const signed char* wsrc1 = Wi16 + woff;
    const int ldst = tid * 16;      // LDS dest: uniform + lane*16
    const size_t WQ8 = (size_t)8 * H_ * 16;    // 8 k8-chunks of W

    f32x16 accR = {}, accI = {};

    // A slots: [band-parity][8], batch-loaded one band ahead
    f16x8 aS[2][8];

    // ---- prologue: band 0 A batch + band 0 W into buf 0
    #pragma unroll
    for (int p = 0; p < 8; p++) {
        aS[0][p] = *(const f16x8*)pA;  pA += strA;
    }
    gll16(wsrc0,       sW + 0 * 4096 + ldst);   // arr0 q0..7
    gll16(wsrc0 + WQ8, sW + 1 * 4096 + ldst);   // arr0 q8..15
    gll16(wsrc1,       sW + 2 * 4096 + ldst);   // arr1 q0..7
    gll16(wsrc1 + WQ8, sW + 3 * 4096 + ldst);   // arr1 q8..15
    __syncthreads();

    const int lbase = half * 512 + c32 * 16;    // per-lane LDS read base
    const size_t WBAND = (size_t)16 * H_ * 16;  // per-band W bytes per array

    #pragma unroll
    for (int s = 0; s < 8; s++) {
        const int cur = s & 1;
        const int nxt = cur ^ 1;

        // ---- prefetch band s+1 FIRST: 4 gll16 -> other LDS buffer, plus
        //      its 8 A chunk loads -> other slot set. By the band-end
        //      barrier these are ~4 ks old => vmcnt(0) drain ~free.
        if (s < 7) {
            size_t wadd = (size_t)(s + 1) * WBAND;
            gll16(wsrc0 + wadd,       sW + nxt * 16384 + 0 * 4096 + ldst);
            gll16(wsrc0 + wadd + WQ8, sW + nxt * 16384 + 1 * 4096 + ldst);
            gll16(wsrc1 + wadd,       sW + nxt * 16384 + 2 * 4096 + ldst);
            gll16(wsrc1 + wadd + WQ8, sW + nxt * 16384 + 3 * 4096 + ldst);
            #pragma unroll
            for (int p = 0; p < 8; p++) {
                aS[nxt][p] = *(const f16x8*)pA;  pA += strA;
            }
        }

        // ---- 4 k-steps (K=32 each) from buf[cur]
        #pragma unroll
        for (int ks = 0; ks < 4; ks++) {
            int off = cur * 16384 + ks * 2048 + lbase;   // q = ks*4 + 2j + half
            f16x8 wr0 = *(const f16x8*)&sW[off];                  // arr0 j0
            f16x8 wr1 = *(const f16x8*)&sW[off + 1024];           // arr0 j1
            f16x8 wi0 = *(const f16x8*)&sW[off + 8192];           // arr1 j0
            f16x8 wi1 = *(const f16x8*)&sW[off + 8192 + 1024];    // arr1 j1
            // swapped operands: D[h][m] += W^T[h][k] * xt[m][k]
            accR = __builtin_amdgcn_mfma_f32_32x32x16_f16(wr0, aS[cur][ks*2+0], accR, 0, 0, 0);
            accI = __builtin_amdgcn_mfma_f32_32x32x16_f16(wi0, aS[cur][ks*2+0], accI, 0, 0, 0);
            accR = __builtin_amdgcn_mfma_f32_32x32x16_f16(wr1, aS[cur][ks*2+1], accR, 0, 0, 0);
            accI = __builtin_amdgcn_mfma_f32_32x32x16_f16(wi1, aS[cur][ks*2+1], accI, 0, 0, 0);
        }
        if (s < 7) __syncthreads();
    }

    // ---- epilogue (phasor-product): lane = one output row; 16 h values.
    // Per term accumulate a=|zr|, c=s*zi, and the complex product of
    // w = 1 + e^{-2a}(cos 2c, -sin 2c). ONE log + ONE atan2 per 16 terms:
    //   sum lr = sum a - 16*LOG2 + 0.5*log|P|^2      (exact)
    //   sum li = sum c + angle(P)                    (exact mod 2pi)
    // Winding (2pi*k) is invisible: partials are summed then consumed by
    // sincos in lse_final; mode-1 oim is principal-value atan2 of sums.
    const int hbase = hs * 32 + 4 * half;
    float Apos = 0.f, Cpos = 0.f, Aneg = 0.f, Cneg = 0.f;
    float Ppr = 1.f, Ppi = 0.f, Pnr = 1.f, Pni = 0.f;
    #pragma unroll
    for (int reg = 0; reg < 16; reg++) {
        int h = hbase + (reg & 3) + 8 * (reg >> 2);
        float brv = br[h], biv = bi[h];
        float tr = accR[reg];
        float ti = accI[reg];
        // pos: z = (tr+brv) + i(ti+biv)
        {
            float zr = tr + brv, zi = ti + biv;
            float s = (zr < 0.0f) ? -1.0f : 1.0f;
            float a = zr * s, c = zi * s;
            float e = __expf(-2.0f * a);
            float s2, c2; __sincosf(2.0f * c, &s2, &c2);
            float wre = fmaf(e, c2, 1.0f);
            float wim = -e * s2;
            Apos += a; Cpos += c;
            float t0 = Ppr * wre - Ppi * wim;
            Ppi = fmaf(Ppr, wim, Ppi * wre);
            Ppr = t0;
        }
        // neg: z = (brv-tr) + i(biv-ti)
        {
            float zr = brv - tr, zi = biv - ti;
            float s = (zr < 0.0f) ? -1.0f : 1.0f;
            float a = zr * s, c = zi * s;
            float e = __expf(-2.0f * a);
            float s2, c2; __sincosf(2.0f * c, &s2, &c2);
            float wre = fmaf(e, c2, 1.0f);
            float wim = -e * s2;
            Aneg += a; Cneg += c;
            float t0 = Pnr * wre - Pni * wim;
            Pni = fmaf(Pnr, wim, Pni * wre);
            Pnr = t0;
        }
    }
    float pr = Apos - 16.0f * LOG2C
             + 0.5f * __logf(fmaf(Ppr, Ppr, Ppi * Ppi));
    float pi = Cpos + atan2_full(Ppi, Ppr);
    float nr = Aneg - 16.0f * LOG2C
             + 0.5f * __logf(fmaf(Pnr, Pnr, Pni * Pni));
    float ni = Cneg + atan2_full(Pni, Pnr);

    pr += __shfl_xor(pr, 32, 64);
    pi += __shfl_xor(pi, 32, 64);
    nr += __shfl_xor(nr, 32, 64);
    ni += __shfl_xor(ni, 32, 64);
    if (half == 0) {
        // coalesced: 32 lanes write 512B; each (hs,row) written exactly once
        part[(size_t)hs * M_ + m0 + c32] = make_float4(pr, pi, nr, ni);
    }
}

// --- reduce the 128 h-slice partials per row ---
__global__ __launch_bounds__(64) void reduce_hb(
    const float4* __restrict__ part, float4* __restrict__ red)
{
    int row = blockIdx.x * 64 + threadIdx.x;
    float a0 = 0.f, a1 = 0.f, a2 = 0.f, a3 = 0.f;
    #pragma unroll 8
    for (int hb = 0; hb < NHB2_; hb++) {
        float4 v = part[(size_t)hb * M_ + row];
        a0 += v.x; a1 += v.y; a2 += v.z; a3 += v.w;
    }
    red[row] = make_float4(a0, a1, a2, a3);
}

// --- final logsumexp over 32 complex values per batch element ---
__global__ __launch_bounds__(64) void lse_final(
    const float4* __restrict__ red, float* __restrict__ out, int mode)
{
    int b = blockIdx.x * 64 + threadIdx.x;
    float re[32], im[32];
    #pragma unroll
    for (int t = 0; t < T_; t++) {
        float4 v = red[t * B_ + b];
        re[t]      = v.x; im[t]      = v.y;
        re[16 + t] = v.z; im[16 + t] = v.w;
    }
    float m = re[0];
    #pragma unroll
    for (int k = 1; k < 32; k++) m = fmaxf(m, re[k]);
    float Sr = 0.f, Si = 0.f;
    #pragma unroll
    for (int k = 0; k < 32; k++) {
        float mag = expf(re[k] - m);
        float s, c;
        sincosf(im[k], &s, &c);   // |im| can be tens of rad: libm reduction
        Sr = fmaf(mag, c, Sr);
        Si = fmaf(mag, s, Si);
    }
    float ore = 0.5f * logf(fmaf(Sr, Sr, Si * Si)) + m;
    float oim = atan2f(Si, Sr);
    if (mode == 0) out[b] = ore;
    else { out[b] = ore; out[B_ + b] = oim; }
}

// =======================================================================
// FALLBACK PATH — round-4 fp32 kernels (verified passing), used only if
// ws_size is too small for the packs.
// =======================================================================
#define FBM 128
#define FBH 64
#define FHC 4
#define FHBG (H_/(FBH*FHC))
#define FBK 16
#define FASTR 132
#define FPS (FHBG*M_)

__global__ __launch_bounds__(256, 3) void gemm_epi_fb(
    const float* __restrict__ x, const int* __restrict__ trans,
    const float* __restrict__ Wr, const float* __restrict__ Wi,
    const float* __restrict__ br, const float* __restrict__ bi,
    float* __restrict__ part)
{
    __shared__ float As[FBK * FASTR];
    __shared__ float Brs[FBK * FBH];
    __shared__ float Bis[FBK * FBH];

    const int tid = threadIdx.x;
    const int tx = tid & 15;
    const int ty = tid >> 4;
    const int hbg = blockIdx.x;
    const int m0 = blockIdx.y * FBM;
    const int t_band = m0 >> 10;
    const int* __restrict__ trow = trans + t_band * N_;

    float pr[8] = {}, pi[8] = {}, nr[8] = {}, ni[8] = {};

    for (int hc = 0; hc < FHC; hc++) {
        const int h0 = (hbg * FHC + hc) * FBH;
        float accre[8][4] = {}, accim[8][4] = {};
        for (int k0 = 0; k0 < N_; k0 += FBK) {
            #pragma unroll
            for (int p = 0; p < 8; p++) {
                int idx = tid + p * 256;
                int kk = idx & 15, r = idx >> 4;
                int b = (m0 + r) & (B_ - 1);
                As[kk * FASTR + r] = x[(size_t)b * N_ + trow[k0 + kk]];
            }
            {
                int r = tid >> 4, c4 = tid & 15;
                *(float4*)(Brs + r * FBH + c4 * 4) =
                    *(const float4*)(Wr + (size_t)(k0 + r) * H_ + h0 + c4 * 4);
                *(float4*)(Bis + r * FBH + c4 * 4) =
                    *(const float4*)(Wi + (size_t)(k0 + r) * H_ + h0 + c4 * 4);
            }
            __syncthreads();
            #pragma unroll
            for (int k = 0; k < FBK; k++) {
                float a[8], wr[4], wi[4];
                *(float4*)&a[0]  = *(float4*)&As[k * FASTR + ty * 8];
                *(float4*)&a[4]  = *(float4*)&As[k * FASTR + ty * 8 + 4];
                *(float4*)&wr[0] = *(float4*)&Brs[k * FBH + tx * 4];
                *(float4*)&wi[0] = *(float4*)&Bis[k * FBH + tx * 4];
                #pragma unroll
                for (int i = 0; i < 8; i++)
                    #pragma unroll
                    for (int j = 0; j < 4; j++) {
                        accre[i][j] = fmaf(a[i], wr[j], accre[i][j]);
                        accim[i][j] = fmaf(a[i], wi[j], accim[i][j]);
                    }
            }
            __syncthreads();
        }
        float brv[4], biv[4];
        #pragma unroll
        for (int j = 0; j < 4; j++) {
            brv[j] = br[h0 + tx * 4 + j];
            biv[j] = bi[h0 + tx * 4 + j];
        }
        #pragma unroll
        for (int i = 0; i < 8; i++)
            #pragma unroll
            for (int j = 0; j < 4; j++) {
                float tr = accre[i][j], ti = accim[i][j];
                float lr, li;
                log_cosh_c(tr + brv[j], ti + biv[j], lr, li);
                pr[i] += lr; pi[i] += li;
                log_cosh_c(brv[j] - tr, biv[j] - ti, lr, li);
                nr[i] += lr; ni[i] += li;
            }
    }
    #pragma unroll
    for (int i = 0; i < 8; i++) {
        float a0 = pr[i], a1 = pi[i], a2 = nr[i], a3 = ni[i];
        #pragma unroll
        for (int off = 1; off < 16; off <<= 1) {
            a0 += __shfl_xor(a0, off, 64);
            a1 += __shfl_xor(a1, off, 64);
            a2 += __shfl_xor(a2, off, 64);
            a3 += __shfl_xor(a3, off, 64);
        }
        if (tx == 0) {
            int row = m0 + ty * 8 + i;
            part[0 * FPS + hbg * M_ + row] = a0;
            part[1 * FPS + hbg * M_ + row] = a1;
            part[2 * FPS + hbg * M_ + row] = a2;
            part[3 * FPS + hbg * M_ + row] = a3;
        }
    }
}

__global__ __launch_bounds__(256) void sum_lse_fb(
    const float* __restrict__ part, float* __restrict__ out, int mode)
{
    int b = blockIdx.x * 256 + threadIdx.x;
    float re[32], im[32];
    #pragma unroll
    for (int t = 0; t < T_; t++) {
        int row = t * B_ + b;
        float a0 = 0.f, a1 = 0.f, a2 = 0.f, a3 = 0.f;
        for (int hb = 0; hb < FHBG; hb++) {
            a0 += part[0 * FPS + hb * M_ + row];
            a1 += part[1 * FPS + hb * M_ + row];
            a2 += part[2 * FPS + hb * M_ + row];
            a3 += part[3 * FPS + hb * M_ + row];
        }
        re[t]      = a0; im[t]      = a1;
        re[16 + t] = a2; im[16 + t] = a3;
    }
    float m = re[0];
    #pragma unroll
    for (int k = 1; k < 32; k++) m = fmaxf(m, re[k]);
    float Sr = 0.f, Si = 0.f;
    #pragma unroll
    for (int k = 0; k < 32; k++) {
        float mag = expf(re[k] - m);
        float s, c;
        sincosf(im[k], &s, &c);
        Sr = fmaf(mag, c, Sr);
        Si = fmaf(mag, s, Si);
    }
    float ore = 0.5f * logf(fmaf(Sr, Sr, Si * Si)) + m;
    float oim = atan2f(Si, Sr);
    if (mode == 0) out[b] = ore;
    else { out[b] = ore; out[B_ + b] = oim; }
}

// =======================================================================

extern "C" void kernel_launch(void* const* d_in, const int* in_sizes, int n_in,
                              void* d_out, int out_size, void* d_ws, size_t ws_size,
                              hipStream_t stream) {
    const float *x = nullptr, *Wr = nullptr, *Wi = nullptr, *br = nullptr, *bi = nullptr;
    const int *trans = nullptr;
    for (int i = 0; i < n_in; i++) {
        int s = in_sizes[i];
        if (s == B_ * N_ && !x)            x  = (const float*)d_in[i];
        else if (s == N_ * H_)             { if (!Wr) Wr = (const float*)d_in[i];
                                             else if (!Wi) Wi = (const float*)d_in[i]; }
        else if (s == H_)                  { if (!br) br = (const float*)d_in[i];
                                             else if (!bi) bi = (const float*)d_in[i]; }
        else if (s == T_ * N_ && !trans)   trans = (const int*)d_in[i];
    }
    if (!x)     x     = (const float*)d_in[0];
    if (!Wr)    Wr    = (const float*)d_in[1];
    if (!Wi)    Wi    = (const float*)d_in[2];
    if (!br)    br    = (const float*)d_in[3];
    if (!bi)    bi    = (const float*)d_in[4];
    if (!trans) trans = (const int*)d_in[5];

    float* out = (float*)d_out;
    const int mode = (out_size == B_) ? 0 : 1;

    const size_t NEED = (size_t)2 * M_ * N_          // A16 (f16)
                      + (size_t)4 * N_ * H_          // Wr16+Wi16 (f16)
                      + (size_t)NHB2_ * M_ * 16      // float4 partials
                      + (size_t)M_ * 16;             // float4 reduced

    if (ws_size >= NEED) {
        signed char* A16  = (signed char*)d_ws;
        signed char* Wr16 = A16  + (size_t)2 * M_ * N_;
        signed char* Wi16 = Wr16 + (size_t)2 * N_ * H_;
        float4* part = (float4*)(Wi16 + (size_t)2 * N_ * H_);
        float4* red  = part + (size_t)NHB2_ * M_;

        dim3 ga(128, 4);
        prep_A16<<<ga, 256, 0, stream>>>(x, trans, A16);
        dim3 gw((N_ / 8) * H_ / 256, 2);
        prep_W16<<<gw, 256, 0, stream>>>(Wr, Wi, Wr16, Wi16);
        gemm_f16<<<128 * 128, 256, 0, stream>>>(A16, Wr16, Wi16,
                                                br, bi, part);
        reduce_hb<<<M_ / 64, 64, 0, stream>>>(part, red);
        lse_final<<<B_ / 64, 64, 0, stream>>>(red, out, mode);
    } else {
        float* part = (float*)d_ws;
        dim3 grid(FHBG, M_ / FBM);
        gemm_epi_fb<<<grid, 256, 0, stream>>>(x, trans, Wr, Wi, br, bi, part);
        sum_lse_fb<<<B_ / 256, 256, 0, stream>>>(part, out, mode);
    }
}